// Round 4
// baseline (423.494 us; speedup 1.0000x reference)
//
#include <hip/hip_runtime.h>
#include <hip/hip_fp16.h>

typedef _Float16 f16;
typedef __attribute__((ext_vector_type(4))) _Float16 f16x4;
typedef __attribute__((ext_vector_type(8))) _Float16 f16x8;
typedef __attribute__((ext_vector_type(4))) float f32x4;

#define MFMA_F16(a,b,c) __builtin_amdgcn_mfma_f32_16x16x32_f16((a),(b),(c),0,0,0)

// async 16B/lane global->LDS DMA; global addr per-lane, LDS base wave-uniform
__device__ __forceinline__ void gl_lds16(const f16* g, f16* l) {
  __builtin_amdgcn_global_load_lds(
      (const __attribute__((address_space(1))) unsigned int*)g,
      (__attribute__((address_space(3))) unsigned int*)l, 16, 0, 0);
}

// ---------------------------------------------------------------------------
// Fragment-chunk packing (all DMA-ready, 1KB contiguous chunks):
//  input pack (x/W, [rows][256]): per 128-row tile, chunk (rt,ks8) idx rt*8+ks8
//    (rt 0..7, ks8 0..7): lane(q,c): [row=rt*16+c][k=ks8*32+q*8 .. +7]
//  Q/K workspace (per b,h; 16 T-tiles of 64 seq x 128 k): chunk (jt,ks) idx
//    jt*4+ks: lane(q,c): [seq=T*64+jt*16+c][k=ks*32+q*8]
//  V workspace: chunk (ct,ks2) idx ct*2+ks2: lane(q,c): [d=ct*16+c][kv=T*64+ks2*32+q*8]
// HISTORY: R3 setprio in this lockstep (barrier-synced) attn regressed 37%
//  (T5 needs phase-split roles, m190); packed bias could not help because the
//  bias cost is LATENCY (loads consumed one QK-cluster after issue), not TA
//  throughput. R4: setprio removed; bias ping-ponged 1 full iter ahead.
// ---------------------------------------------------------------------------

// ---------------------------------------------------------------------------
// Pack pass: fp32 row-major -> f16 fragment-chunk tiles (coalesced in+out).
// Grid 280: 0..127 x1 tiles, 128..255 x2 tiles, 256..279 {wq,wk,wv} tiles.
// ---------------------------------------------------------------------------
__global__ __launch_bounds__(256) void conv_pack(
    const float* __restrict__ x1, const float* __restrict__ x2,
    const float* __restrict__ wq, const float* __restrict__ wk,
    const float* __restrict__ wv,
    f16* __restrict__ x1p, f16* __restrict__ x2p, f16* __restrict__ wp) {
  __shared__ f16 S[128][264];
  const int id = blockIdx.x, tid = threadIdx.x;
  const float* src;
  f16* dst;
  if (id < 128) {
    src = x1 + (size_t)id * 32768; dst = x1p + (size_t)id * 32768;
  } else if (id < 256) {
    src = x2 + (size_t)(id - 128) * 32768; dst = x2p + (size_t)(id - 128) * 32768;
  } else {
    const int wsel = (id - 256) >> 3, wt = (id - 256) & 7;
    const float* wsrc = (wsel == 0) ? wq : (wsel == 1) ? wk : wv;
    src = wsrc + (size_t)wt * 32768;
    dst = wp + (size_t)wsel * 262144 + (size_t)wt * 32768;
  }
#pragma unroll 8
  for (int i = 0; i < 32; i++) {
    int f = i * 256 + tid;           // 8192 float4s = 128 rows x 64
    int row = f >> 6, c4 = f & 63;
    float4 v = *(const float4*)(src + (size_t)row * 256 + c4 * 4);
    f16x4 hh; hh[0] = (f16)v.x; hh[1] = (f16)v.y; hh[2] = (f16)v.z; hh[3] = (f16)v.w;
    *(f16x4*)&S[row][c4 * 4] = hh;
  }
  __syncthreads();
#pragma unroll 8
  for (int i = 0; i < 16; i++) {
    int u = i * 256 + tid;           // 4096 b128 units
    int chunk = u >> 6, l2 = u & 63;
    int q = l2 >> 4, c = l2 & 15;
    int row = (chunk >> 3) * 16 + c, k = (chunk & 7) * 32 + q * 8;
    f16x8 v = *(const f16x8*)&S[row][k];
    *(f16x8*)(dst + (size_t)u * 8) = v;
  }
}

// ---------------------------------------------------------------------------
// QKV GEMM v4: pure-DMA staging (zero staging VALU). grid (128 xt, 8 h, 3 z).
// BM=128(hd) x BN=128(x) x BK=64, 4 K-iters, double-buffered, one barrier/iter,
// DMA one iter in flight. 512 thr = 8 waves (2 M-groups x 4 N-groups).
// z==2 (V) swaps operand roles so C rows = x (kv-runs) for the V layout.
// LDS 64KB -> 2 blocks/CU (16 waves/CU).
// ---------------------------------------------------------------------------
__global__ __launch_bounds__(512) __attribute__((amdgpu_waves_per_eu(4, 4)))
void gemm_qkv(const f16* __restrict__ x1p, const f16* __restrict__ x2p,
              const f16* __restrict__ wp,
              const float* __restrict__ wqb, const float* __restrict__ wkb,
              const float* __restrict__ wvb,
              f16* __restrict__ Qp, f16* __restrict__ Kp, f16* __restrict__ Vp,
              float qscale) {
  __shared__ f16 Wl[2][8192];
  __shared__ f16 Xl[2][8192];
  const int z = blockIdx.z;
  const f16* Xp = (z == 0) ? x1p : x2p;
  const float* bias = (z == 0) ? wqb : (z == 1) ? wkb : wvb;
  f16* outp = (z == 0) ? Qp : (z == 1) ? Kp : Vp;
  const float sc = (z == 0) ? qscale : 1.0f;

  const int tid = threadIdx.x, lane = tid & 63, wid = tid >> 6;
  const int col = lane & 15, quad = lane >> 4;
  const int xt = blockIdx.x, h = blockIdx.y;
  const int wr = wid >> 2, xc = wid & 3;  // wave M-group / N-group
  const f16* Xb = Xp + (size_t)xt * 32768;
  const f16* Wb = wp + (size_t)z * 262144 + (size_t)h * 32768;

  // stage K-iter T: chunks ks8 = T*2 + {0,1}; per wave 2 W + 2 X chunks
#define QISSUE(T, bufi)                                                   \
  {                                                                       \
    _Pragma("unroll") for (int j = 0; j < 2; j++) {                       \
      int lc = wid * 2 + j;                                               \
      int rt = lc >> 1, ksl = lc & 1;                                     \
      gl_lds16(Wb + (size_t)((rt * 8 + (T) * 2 + ksl) << 9) + lane * 8,   \
               &Wl[bufi][lc * 512]);                                      \
      gl_lds16(Xb + (size_t)((rt * 8 + (T) * 2 + ksl) << 9) + lane * 8,   \
               &Xl[bufi][lc * 512]);                                      \
    }                                                                     \
  }

  QISSUE(0, 0);
  QISSUE(1, 1);

  f32x4 acc[4][2];
#pragma unroll
  for (int i = 0; i < 4; i++)
#pragma unroll
    for (int j = 0; j < 2; j++) acc[i][j] = (f32x4){0.f, 0.f, 0.f, 0.f};

  __syncthreads();

  for (int t = 0; t < 4; ++t) {
    const int buf = t & 1;
    const f16* Ra = (z == 2) ? Xl[buf] : Wl[buf];  // A-operand (C rows)
    const f16* Cb = (z == 2) ? Wl[buf] : Xl[buf];  // B-operand (C cols)
#pragma unroll
    for (int ksl = 0; ksl < 2; ksl++) {
      f16x8 af[4], bf[2];
#pragma unroll
      for (int i = 0; i < 4; i++)
        af[i] = *(const f16x8*)&Ra[((wr * 4 + i) * 2 + ksl) * 512 + lane * 8];
#pragma unroll
      for (int j = 0; j < 2; j++)
        bf[j] = *(const f16x8*)&Cb[((xc * 2 + j) * 2 + ksl) * 512 + lane * 8];
#pragma unroll
      for (int i = 0; i < 4; i++)
#pragma unroll
        for (int j = 0; j < 2; j++) acc[i][j] = MFMA_F16(af[i], bf[j], acc[i][j]);
    }
    __syncthreads();
    if (t + 2 < 4) QISSUE(t + 2, buf);
  }

  if (z < 2) {
    // C rows = hd (k-runs over r), cols = bn2 -> Q/K packed chunks
#pragma unroll
    for (int i = 0; i < 4; i++) {
      const int k0h = wr * 64 + i * 16 + quad * 4;  // k within head; &7 in {0,4}
      float4 bq = *(const float4*)(bias + h * 128 + k0h);
      const int ks2 = k0h >> 5, q2 = (k0h >> 3) & 3, lo = k0h & 7;
#pragma unroll
      for (int j = 0; j < 2; j++) {
        const int bn2 = xt * 128 + xc * 32 + j * 16 + col;
        const int b = bn2 >> 10, n2 = bn2 & 1023;
        const int T = n2 >> 6, jt = (n2 >> 4) & 3, c2 = n2 & 15;
        f16x4 pk;
#pragma unroll
        for (int r = 0; r < 4; r++)
          pk[r] = (f16)((acc[i][j][r] + ((const float*)&bq)[r]) * sc);
        *(f16x4*)(outp + (size_t)(b * 8 + h) * 131072 + T * 8192 +
                  (jt * 4 + ks2) * 512 + (q2 * 16 + c2) * 8 + lo) = pk;
      }
    }
  } else {
    // C rows = bn2 (kv-runs over r), cols = hd -> V packed chunks
#pragma unroll
    for (int j = 0; j < 2; j++) {
      const int d = xc * 32 + j * 16 + col;  // d within head
      const float bv = bias[h * 128 + d];
      const int ct = d >> 4, cc = d & 15;
#pragma unroll
      for (int i = 0; i < 4; i++) {
        const int bn2 = xt * 128 + wr * 64 + i * 16 + quad * 4;
        const int b = bn2 >> 10, n2 = bn2 & 1023;
        const int T = n2 >> 6, kv6 = n2 & 63;
        const int ks2 = kv6 >> 5, qv = (kv6 >> 3) & 3, jj = kv6 & 7;
        f16x4 pk;
#pragma unroll
        for (int r = 0; r < 4; r++) pk[r] = (f16)(acc[i][j][r] + bv);
        *(f16x4*)(outp + (size_t)(b * 8 + h) * 131072 + T * 8192 +
                  (ct * 2 + ks2) * 512 + (qv * 16 + cc) * 8 + jj) = pk;
      }
    }
  }
}

// ---------------------------------------------------------------------------
// Proj GEMM: out[16384,128] = A[16384,1024](f16) @ W[128,1024]^T + b, fp32.
// BM=64, BN=64, grid (256,2) -> 2 blocks/CU (8 waves/CU).
// ---------------------------------------------------------------------------
__global__ __launch_bounds__(256) void gemm_proj(const f16* __restrict__ A,
                                                 const float* __restrict__ W,
                                                 const float* __restrict__ bias,
                                                 float* __restrict__ out) {
  constexpr int LD = 72;
  __shared__ f16 As[64][LD];
  __shared__ f16 Bs[64][LD];
  const int tid = threadIdx.x, lane = tid & 63, wid = tid >> 6;
  const int col = lane & 15, quad = lane >> 4;
  const int wm = (wid >> 1) * 32, wn = (wid & 1) * 32;
  const int m0 = blockIdx.x * 64, n0 = blockIdx.y * 64;

  f32x4 acc[2][2];
#pragma unroll
  for (int i = 0; i < 2; i++)
#pragma unroll
    for (int j = 0; j < 2; j++) acc[i][j] = (f32x4){0.f, 0.f, 0.f, 0.f};

  for (int kt = 0; kt < 16; ++kt) {
    const int k0 = kt * 64;
#pragma unroll
    for (int i = 0; i < 2; i++) {
      int f = i * 256 + tid;
      int r = f >> 3, ch = f & 7;
      *(f16x8*)&As[r][ch * 8] = *(const f16x8*)(A + (size_t)(m0 + r) * 1024 + k0 + ch * 8);
    }
#pragma unroll
    for (int i = 0; i < 4; i++) {
      int f = i * 256 + tid;
      int r = f >> 4, c4 = f & 15;
      float4 v = *(const float4*)(W + (size_t)(n0 + r) * 1024 + k0 + c4 * 4);
      f16x4 hh; hh[0] = (f16)v.x; hh[1] = (f16)v.y; hh[2] = (f16)v.z; hh[3] = (f16)v.w;
      *(f16x4*)&Bs[r][c4 * 4] = hh;
    }
    __syncthreads();
#pragma unroll
    for (int ks = 0; ks < 2; ks++) {
      f16x8 af[2], bf[2];
#pragma unroll
      for (int i = 0; i < 2; i++) af[i] = *(const f16x8*)&As[wm + i * 16 + col][ks * 32 + quad * 8];
#pragma unroll
      for (int j = 0; j < 2; j++) bf[j] = *(const f16x8*)&Bs[wn + j * 16 + col][ks * 32 + quad * 8];
#pragma unroll
      for (int i = 0; i < 2; i++)
#pragma unroll
        for (int j = 0; j < 2; j++) acc[i][j] = MFMA_F16(af[i], bf[j], acc[i][j]);
    }
    __syncthreads();
  }
#pragma unroll
  for (int j = 0; j < 2; j++) {
    const int c = n0 + wn + j * 16 + col;
    const float bv = bias[c];
#pragma unroll
    for (int i = 0; i < 2; i++) {
      const int r0 = m0 + wm + i * 16 + quad * 4;
#pragma unroll
      for (int r = 0; r < 4; r++)
        out[(size_t)(r0 + r) * 128 + c] = acc[i][j][r] + bv;
    }
  }
}

// ---------------------------------------------------------------------------
// Fused attention v5: 256 thr = 4 waves x 32 q-rows. No setprio (R3 lesson:
// lockstep waves, T5 regressed 37%). Bias loads PING-PONG PREFETCHED one full
// iteration ahead (issue at top of iter t for t+1; latency window = QK+SM+PV
// ~600cy instead of QK-only ~250cy). Unroll-by-2 keeps breg indexing static
// (rule #20: runtime-indexed float4 arrays spill to scratch).
// LDS 80KB -> 2 blocks/CU.
// ---------------------------------------------------------------------------
__global__ __launch_bounds__(256, 2)
void attn_fused(const f16* __restrict__ Qp, const f16* __restrict__ Kp,
                const f16* __restrict__ Vp, const float* __restrict__ Bm,
                f16* __restrict__ O) {
  __shared__ f16 Ksl[2][8192];
  __shared__ f16 Vtl[2][8192];
  __shared__ f16 Ps[8192];
  const int tid = threadIdx.x, lane = tid & 63, wid = tid >> 6;  // wid 0..3
  const int col = lane & 15, quad = lane >> 4;
  const int id = blockIdx.x;
  const int mt = (id >> 3) & 7;
  const int bh = ((id >> 6) << 3) | (id & 7);  // 8 m-tiles of one bh per XCD
  const int b = bh >> 3, h = bh & 7;
  const int m0 = mt * 128;
  const int wm = wid * 32;  // wave's 32 q-rows

  const f16* Qb = Qp + (size_t)bh * 131072;
  const f16* Kb = Kp + (size_t)bh * 131072;
  const f16* Vb = Vp + (size_t)bh * 131072;

  // waves 0-1 stage K chunks, waves 2-3 stage V chunks (8 each)
#define AISSUE(T, bufi)                                                       \
  {                                                                           \
    if (wid < 2) {                                                            \
      _Pragma("unroll") for (int j = 0; j < 8; j++)                           \
          gl_lds16(Kb + (size_t)(T) * 8192 + (wid * 8 + j) * 512 + lane * 8,  \
                   &Ksl[bufi][(wid * 8 + j) * 512]);                          \
    } else {                                                                  \
      _Pragma("unroll") for (int j = 0; j < 8; j++)                           \
          gl_lds16(Vb + (size_t)(T) * 8192 + ((wid - 2) * 8 + j) * 512 + lane * 8, \
                   &Vtl[bufi][((wid - 2) * 8 + j) * 512]);                    \
    }                                                                         \
  }

  AISSUE(0, 0);
  AISSUE(1, 1);

  f16x8 qf[2][4];
#pragma unroll
  for (int qc = 0; qc < 2; qc++) {
    const int m = m0 + wm + qc * 16;
    const int T = m >> 6, jt2 = (m >> 4) & 3;
#pragma unroll
    for (int ks = 0; ks < 4; ks++)
      qf[qc][ks] = *(const f16x8*)(Qb + T * 8192 + (jt2 * 4 + ks) * 512 + lane * 8);
  }

  // per-qc bias row base (row = m0 + wm + qc*16 + col)
  const float* Brow0 = Bm + (size_t)(m0 + wm + col) * 1024;
  const float* Brow1 = Bm + (size_t)(m0 + wm + 16 + col) * 1024;

#define LOADB(dst, T)                                                     \
  {                                                                       \
    const int nn = (T) * 64 + quad * 4;                                   \
    _Pragma("unroll") for (int jt = 0; jt < 4; jt++) {                    \
      dst[0][jt] = *(const float4*)(Brow0 + nn + jt * 16);                \
      dst[1][jt] = *(const float4*)(Brow1 + nn + jt * 16);                \
    }                                                                     \
  }

  float4 bA[2][4], bB[2][4];
  LOADB(bA, 0);

  f32x4 oacc[2][8];
  float l[2] = {0.f, 0.f};
#pragma unroll
  for (int qc = 0; qc < 2; qc++)
#pragma unroll
    for (int ct = 0; ct < 8; ct++) oacc[qc][ct] = (f32x4){0.f, 0.f, 0.f, 0.f};

  __syncthreads();

  // One kv-tile iteration. BC = bias regs for this iter (consumed at softmax);
  // BN = bias regs prefetched here for iter T+1 (in flight across QK+SM+PV).
#define AITER(T, BC, BN)                                                      \
  {                                                                           \
    const int buf = (T) & 1;                                                  \
    LOADB(BN, ((T) + 1) & 15);                                                \
    f32x4 s[2][4];                                                            \
    _Pragma("unroll") for (int qc = 0; qc < 2; qc++)                          \
        _Pragma("unroll") for (int jt = 0; jt < 4; jt++)                      \
            s[qc][jt] = (f32x4){0.f, 0.f, 0.f, 0.f};                          \
    _Pragma("unroll") for (int ks = 0; ks < 4; ks++) {                        \
      f16x8 kf[4];                                                            \
      _Pragma("unroll") for (int jt = 0; jt < 4; jt++)                        \
          kf[jt] = *(const f16x8*)&Ksl[buf][(jt * 4 + ks) * 512 + lane * 8];  \
      _Pragma("unroll") for (int jt = 0; jt < 4; jt++)                        \
          _Pragma("unroll") for (int qc = 0; qc < 2; qc++)                    \
              s[qc][jt] = MFMA_F16(kf[jt], qf[qc][ks], s[qc][jt]);            \
    }                                                                         \
    _Pragma("unroll") for (int qc = 0; qc < 2; qc++) {                        \
      const int m = wm + qc * 16 + col;                                       \
      _Pragma("unroll") for (int jt = 0; jt < 4; jt++) {                      \
        const float* bv = (const float*)&BC[qc][jt];                          \
        float p0 = __expf(s[qc][jt][0] + bv[0]);                              \
        float p1 = __expf(s[qc][jt][1] + bv[1]);                              \
        float p2 = __expf(s[qc][jt][2] + bv[2]);                              \
        float p3 = __expf(s[qc][jt][3] + bv[3]);                              \
        l[qc] += (p0 + p1) + (p2 + p3);                                       \
        f16x4 pk; pk[0] = (f16)p0; pk[1] = (f16)p1;                           \
        pk[2] = (f16)p2; pk[3] = (f16)p3;                                     \
        const int g = (jt * 2 + (quad >> 1)) ^ (col & 7);                     \
        *(f16x4*)&Ps[m * 64 + g * 8 + (quad & 1) * 4] = pk;                   \
      }                                                                       \
    }                                                                         \
    _Pragma("unroll") for (int ks = 0; ks < 2; ks++) {                        \
      f16x8 pf[2];                                                            \
      _Pragma("unroll") for (int qc = 0; qc < 2; qc++) {                      \
        const int m = wm + qc * 16 + col;                                     \
        const int g = (ks * 4 + quad) ^ (col & 7);                            \
        pf[qc] = *(const f16x8*)&Ps[m * 64 + g * 8];                          \
      }                                                                       \
      _Pragma("unroll") for (int ct = 0; ct < 8; ct++) {                      \
        f16x8 vf = *(const f16x8*)&Vtl[buf][(ct * 2 + ks) * 512 + lane * 8];  \
        _Pragma("unroll") for (int qc = 0; qc < 2; qc++)                      \
            oacc[qc][ct] = MFMA_F16(pf[qc], vf, oacc[qc][ct]);                \
      }                                                                       \
    }                                                                         \
    __syncthreads();                                                          \
    if ((T) + 2 < 16) AISSUE((T) + 2, buf);                                   \
  }

  for (int tt = 0; tt < 16; tt += 2) {
    AITER(tt, bA, bB);
    AITER(tt + 1, bB, bA);
  }

#pragma unroll
  for (int qc = 0; qc < 2; qc++) {
    float lw = l[qc];
    lw += __shfl_xor(lw, 16);
    lw += __shfl_xor(lw, 32);
    f16* Ob = O + ((size_t)(b * 1024 + m0 + wm + qc * 16)) * 1024 + h * 128;
#pragma unroll
    for (int r = 0; r < 4; r++) {
      const float lv = __shfl(lw, (lane & 48) | (quad * 4 + r));
      const float inv = 1.0f / lv;
#pragma unroll
      for (int ct = 0; ct < 8; ct++)
        Ob[(size_t)(quad * 4 + r) * 1024 + ct * 16 + col] = (f16)(oacc[qc][ct][r] * inv);
    }
  }
}

extern "C" void kernel_launch(void* const* d_in, const int* in_sizes, int n_in,
                              void* d_out, int out_size, void* d_ws, size_t ws_size,
                              hipStream_t stream) {
  (void)in_sizes; (void)n_in; (void)out_size; (void)ws_size;
  const float* x1  = (const float*)d_in[0];
  const float* x2  = (const float*)d_in[1];
  const float* Bm  = (const float*)d_in[2];
  const float* wq  = (const float*)d_in[3];
  const float* wqb = (const float*)d_in[4];
  const float* wk  = (const float*)d_in[5];
  const float* wkb = (const float*)d_in[6];
  const float* wv  = (const float*)d_in[7];
  const float* wvb = (const float*)d_in[8];
  const float* pw  = (const float*)d_in[9];
  const float* pb  = (const float*)d_in[10];
  float* out = (float*)d_out;

  const size_t MiB = 1024 * 1024;
  f16* Qp  = (f16*)d_ws;                            // 0..32 MiB
  f16* Kp  = (f16*)((char*)d_ws + 32 * MiB);        // 32..64
  f16* Vp  = (f16*)((char*)d_ws + 64 * MiB);        // 64..96
  f16* Ow  = (f16*)((char*)d_ws + 96 * MiB);        // 96..128 (attn output)
  // packed inputs: alive only conv->qkv, then overlaid by Ow
  f16* x1p = (f16*)((char*)d_ws + 96 * MiB);        // 8 MiB
  f16* x2p = (f16*)((char*)d_ws + 104 * MiB);       // 8 MiB
  f16* wp  = (f16*)((char*)d_ws + 112 * MiB);       // 1.5 MiB

  const float scale = 0.0883883476483184f;  // 1/sqrt(128)
  conv_pack<<<dim3(280), dim3(256), 0, stream>>>(x1, x2, wq, wk, wv, x1p, x2p, wp);
  gemm_qkv<<<dim3(128, 8, 3), dim3(512), 0, stream>>>(x1p, x2p, wp, wqb, wkb, wvb,
                                                      Qp, Kp, Vp, scale);
  attn_fused<<<dim3(1024), dim3(256), 0, stream>>>(Qp, Kp, Vp, Bm, Ow);
  gemm_proj<<<dim3(256, 2), dim3(256), 0, stream>>>(Ow, pw, pb, out);
}

// Round 6
// 404.346 us; speedup vs baseline: 1.0474x; 1.0474x over previous
//
#include <hip/hip_runtime.h>
#include <hip/hip_fp16.h>

typedef _Float16 f16;
typedef __attribute__((ext_vector_type(4))) _Float16 f16x4;
typedef __attribute__((ext_vector_type(8))) _Float16 f16x8;
typedef __attribute__((ext_vector_type(4))) float f32x4;

#define MFMA_F16(a,b,c) __builtin_amdgcn_mfma_f32_16x16x32_f16((a),(b),(c),0,0,0)

// async 16B/lane global->LDS DMA; global addr per-lane, LDS base wave-uniform
__device__ __forceinline__ void gl_lds16(const f16* g, f16* l) {
  __builtin_amdgcn_global_load_lds(
      (const __attribute__((address_space(1))) unsigned int*)g,
      (__attribute__((address_space(3))) unsigned int*)l, 16, 0, 0);
}

// ---------------------------------------------------------------------------
// Fragment-chunk packing (all DMA-ready, 1KB contiguous chunks):
//  input pack (x/W, [rows][256]): per 128-row tile, chunk (rt,ks8) idx rt*8+ks8
//    (rt 0..7, ks8 0..7): lane(q,c): [row=rt*16+c][k=ks8*32+q*8 .. +7]
//  Q/K workspace (per b,h; 16 T-tiles of 64 seq x 128 k): chunk (jt,ks) idx
//    jt*4+ks: lane(q,c): [seq=T*64+jt*16+c][k=ks*32+q*8]
//    NOTE: K half-tiles (32 kv) are CONTIGUOUS 4KB: Kb + t*4096, chunks c=0..7
//    map to (jt=(t&1)*2+(c>>2), ks=c&3).
//  V workspace: chunk (ct,ks2) idx ct*2+ks2: lane(q,c): [d=ct*16+c][kv=T*64+ks2*32+q*8]
// HISTORY:
//  R3: setprio in lockstep barrier-synced attn: -37% (T5 needs phase-split).
//  R4: bias ping-pong macro-unroll -> scratch spills (WRITE_SIZE 32->196MB).
//  R5: kv-tile 64->32: LDS 80->40KB -> 3-4 blocks/CU (was 2). R0/R1 showed
//   per-CU work invariance at 2 blocks/CU with 42% idle; only distinct blocks
//   (not barrier-locked waves) can fill barrier/latency idle.
//  (R5 bench was an infra failure — container died; identical resubmit.)
// ---------------------------------------------------------------------------

// ---------------------------------------------------------------------------
// Pack pass: fp32 row-major -> f16 fragment-chunk tiles (coalesced in+out).
// Grid 280: 0..127 x1 tiles, 128..255 x2 tiles, 256..279 {wq,wk,wv} tiles.
// ---------------------------------------------------------------------------
__global__ __launch_bounds__(256) void conv_pack(
    const float* __restrict__ x1, const float* __restrict__ x2,
    const float* __restrict__ wq, const float* __restrict__ wk,
    const float* __restrict__ wv,
    f16* __restrict__ x1p, f16* __restrict__ x2p, f16* __restrict__ wp) {
  __shared__ f16 S[128][264];
  const int id = blockIdx.x, tid = threadIdx.x;
  const float* src;
  f16* dst;
  if (id < 128) {
    src = x1 + (size_t)id * 32768; dst = x1p + (size_t)id * 32768;
  } else if (id < 256) {
    src = x2 + (size_t)(id - 128) * 32768; dst = x2p + (size_t)(id - 128) * 32768;
  } else {
    const int wsel = (id - 256) >> 3, wt = (id - 256) & 7;
    const float* wsrc = (wsel == 0) ? wq : (wsel == 1) ? wk : wv;
    src = wsrc + (size_t)wt * 32768;
    dst = wp + (size_t)wsel * 262144 + (size_t)wt * 32768;
  }
#pragma unroll 8
  for (int i = 0; i < 32; i++) {
    int f = i * 256 + tid;           // 8192 float4s = 128 rows x 64
    int row = f >> 6, c4 = f & 63;
    float4 v = *(const float4*)(src + (size_t)row * 256 + c4 * 4);
    f16x4 hh; hh[0] = (f16)v.x; hh[1] = (f16)v.y; hh[2] = (f16)v.z; hh[3] = (f16)v.w;
    *(f16x4*)&S[row][c4 * 4] = hh;
  }
  __syncthreads();
#pragma unroll 8
  for (int i = 0; i < 16; i++) {
    int u = i * 256 + tid;           // 4096 b128 units
    int chunk = u >> 6, l2 = u & 63;
    int q = l2 >> 4, c = l2 & 15;
    int row = (chunk >> 3) * 16 + c, k = (chunk & 7) * 32 + q * 8;
    f16x8 v = *(const f16x8*)&S[row][k];
    *(f16x8*)(dst + (size_t)u * 8) = v;
  }
}

// ---------------------------------------------------------------------------
// QKV GEMM v4: pure-DMA staging (zero staging VALU). grid (128 xt, 8 h, 3 z).
// BM=128(hd) x BN=128(x) x BK=64, 4 K-iters, double-buffered, one barrier/iter,
// DMA one iter in flight. 512 thr = 8 waves (2 M-groups x 4 N-groups).
// z==2 (V) swaps operand roles so C rows = x (kv-runs) for the V layout.
// LDS 64KB -> 2 blocks/CU (16 waves/CU).
// ---------------------------------------------------------------------------
__global__ __launch_bounds__(512) __attribute__((amdgpu_waves_per_eu(4, 4)))
void gemm_qkv(const f16* __restrict__ x1p, const f16* __restrict__ x2p,
              const f16* __restrict__ wp,
              const float* __restrict__ wqb, const float* __restrict__ wkb,
              const float* __restrict__ wvb,
              f16* __restrict__ Qp, f16* __restrict__ Kp, f16* __restrict__ Vp,
              float qscale) {
  __shared__ f16 Wl[2][8192];
  __shared__ f16 Xl[2][8192];
  const int z = blockIdx.z;
  const f16* Xp = (z == 0) ? x1p : x2p;
  const float* bias = (z == 0) ? wqb : (z == 1) ? wkb : wvb;
  f16* outp = (z == 0) ? Qp : (z == 1) ? Kp : Vp;
  const float sc = (z == 0) ? qscale : 1.0f;

  const int tid = threadIdx.x, lane = tid & 63, wid = tid >> 6;
  const int col = lane & 15, quad = lane >> 4;
  const int xt = blockIdx.x, h = blockIdx.y;
  const int wr = wid >> 2, xc = wid & 3;  // wave M-group / N-group
  const f16* Xb = Xp + (size_t)xt * 32768;
  const f16* Wb = wp + (size_t)z * 262144 + (size_t)h * 32768;

  // stage K-iter T: chunks ks8 = T*2 + {0,1}; per wave 2 W + 2 X chunks
#define QISSUE(T, bufi)                                                   \
  {                                                                       \
    _Pragma("unroll") for (int j = 0; j < 2; j++) {                       \
      int lc = wid * 2 + j;                                               \
      int rt = lc >> 1, ksl = lc & 1;                                     \
      gl_lds16(Wb + (size_t)((rt * 8 + (T) * 2 + ksl) << 9) + lane * 8,   \
               &Wl[bufi][lc * 512]);                                      \
      gl_lds16(Xb + (size_t)((rt * 8 + (T) * 2 + ksl) << 9) + lane * 8,   \
               &Xl[bufi][lc * 512]);                                      \
    }                                                                     \
  }

  QISSUE(0, 0);
  QISSUE(1, 1);

  f32x4 acc[4][2];
#pragma unroll
  for (int i = 0; i < 4; i++)
#pragma unroll
    for (int j = 0; j < 2; j++) acc[i][j] = (f32x4){0.f, 0.f, 0.f, 0.f};

  __syncthreads();

  for (int t = 0; t < 4; ++t) {
    const int buf = t & 1;
    const f16* Ra = (z == 2) ? Xl[buf] : Wl[buf];  // A-operand (C rows)
    const f16* Cb = (z == 2) ? Wl[buf] : Xl[buf];  // B-operand (C cols)
#pragma unroll
    for (int ksl = 0; ksl < 2; ksl++) {
      f16x8 af[4], bf[2];
#pragma unroll
      for (int i = 0; i < 4; i++)
        af[i] = *(const f16x8*)&Ra[((wr * 4 + i) * 2 + ksl) * 512 + lane * 8];
#pragma unroll
      for (int j = 0; j < 2; j++)
        bf[j] = *(const f16x8*)&Cb[((xc * 2 + j) * 2 + ksl) * 512 + lane * 8];
#pragma unroll
      for (int i = 0; i < 4; i++)
#pragma unroll
        for (int j = 0; j < 2; j++) acc[i][j] = MFMA_F16(af[i], bf[j], acc[i][j]);
    }
    __syncthreads();
    if (t + 2 < 4) QISSUE(t + 2, buf);
  }

  if (z < 2) {
    // C rows = hd (k-runs over r), cols = bn2 -> Q/K packed chunks
#pragma unroll
    for (int i = 0; i < 4; i++) {
      const int k0h = wr * 64 + i * 16 + quad * 4;  // k within head; &7 in {0,4}
      float4 bq = *(const float4*)(bias + h * 128 + k0h);
      const int ks2 = k0h >> 5, q2 = (k0h >> 3) & 3, lo = k0h & 7;
#pragma unroll
      for (int j = 0; j < 2; j++) {
        const int bn2 = xt * 128 + xc * 32 + j * 16 + col;
        const int b = bn2 >> 10, n2 = bn2 & 1023;
        const int T = n2 >> 6, jt = (n2 >> 4) & 3, c2 = n2 & 15;
        f16x4 pk;
#pragma unroll
        for (int r = 0; r < 4; r++)
          pk[r] = (f16)((acc[i][j][r] + ((const float*)&bq)[r]) * sc);
        *(f16x4*)(outp + (size_t)(b * 8 + h) * 131072 + T * 8192 +
                  (jt * 4 + ks2) * 512 + (q2 * 16 + c2) * 8 + lo) = pk;
      }
    }
  } else {
    // C rows = bn2 (kv-runs over r), cols = hd -> V packed chunks
#pragma unroll
    for (int j = 0; j < 2; j++) {
      const int d = xc * 32 + j * 16 + col;  // d within head
      const float bv = bias[h * 128 + d];
      const int ct = d >> 4, cc = d & 15;
#pragma unroll
      for (int i = 0; i < 4; i++) {
        const int bn2 = xt * 128 + wr * 64 + i * 16 + quad * 4;
        const int b = bn2 >> 10, n2 = bn2 & 1023;
        const int T = n2 >> 6, kv6 = n2 & 63;
        const int ks2 = kv6 >> 5, qv = (kv6 >> 3) & 3, jj = kv6 & 7;
        f16x4 pk;
#pragma unroll
        for (int r = 0; r < 4; r++) pk[r] = (f16)(acc[i][j][r] + bv);
        *(f16x4*)(outp + (size_t)(b * 8 + h) * 131072 + T * 8192 +
                  (ct * 2 + ks2) * 512 + (qv * 16 + cc) * 8 + jj) = pk;
      }
    }
  }
}

// ---------------------------------------------------------------------------
// Proj GEMM: out[16384,128] = A[16384,1024](f16) @ W[128,1024]^T + b, fp32.
// BM=64, BN=64, grid (256,2) -> 2 blocks/CU (8 waves/CU).
// ---------------------------------------------------------------------------
__global__ __launch_bounds__(256) void gemm_proj(const f16* __restrict__ A,
                                                 const float* __restrict__ W,
                                                 const float* __restrict__ bias,
                                                 float* __restrict__ out) {
  constexpr int LD = 72;
  __shared__ f16 As[64][LD];
  __shared__ f16 Bs[64][LD];
  const int tid = threadIdx.x, lane = tid & 63, wid = tid >> 6;
  const int col = lane & 15, quad = lane >> 4;
  const int wm = (wid >> 1) * 32, wn = (wid & 1) * 32;
  const int m0 = blockIdx.x * 64, n0 = blockIdx.y * 64;

  f32x4 acc[2][2];
#pragma unroll
  for (int i = 0; i < 2; i++)
#pragma unroll
    for (int j = 0; j < 2; j++) acc[i][j] = (f32x4){0.f, 0.f, 0.f, 0.f};

  for (int kt = 0; kt < 16; ++kt) {
    const int k0 = kt * 64;
#pragma unroll
    for (int i = 0; i < 2; i++) {
      int f = i * 256 + tid;
      int r = f >> 3, ch = f & 7;
      *(f16x8*)&As[r][ch * 8] = *(const f16x8*)(A + (size_t)(m0 + r) * 1024 + k0 + ch * 8);
    }
#pragma unroll
    for (int i = 0; i < 4; i++) {
      int f = i * 256 + tid;
      int r = f >> 4, c4 = f & 15;
      float4 v = *(const float4*)(W + (size_t)(n0 + r) * 1024 + k0 + c4 * 4);
      f16x4 hh; hh[0] = (f16)v.x; hh[1] = (f16)v.y; hh[2] = (f16)v.z; hh[3] = (f16)v.w;
      *(f16x4*)&Bs[r][c4 * 4] = hh;
    }
    __syncthreads();
#pragma unroll
    for (int ks = 0; ks < 2; ks++) {
      f16x8 af[2], bf[2];
#pragma unroll
      for (int i = 0; i < 2; i++) af[i] = *(const f16x8*)&As[wm + i * 16 + col][ks * 32 + quad * 8];
#pragma unroll
      for (int j = 0; j < 2; j++) bf[j] = *(const f16x8*)&Bs[wn + j * 16 + col][ks * 32 + quad * 8];
#pragma unroll
      for (int i = 0; i < 2; i++)
#pragma unroll
        for (int j = 0; j < 2; j++) acc[i][j] = MFMA_F16(af[i], bf[j], acc[i][j]);
    }
    __syncthreads();
  }
#pragma unroll
  for (int j = 0; j < 2; j++) {
    const int c = n0 + wn + j * 16 + col;
    const float bv = bias[c];
#pragma unroll
    for (int i = 0; i < 2; i++) {
      const int r0 = m0 + wm + i * 16 + quad * 4;
#pragma unroll
      for (int r = 0; r < 4; r++)
        out[(size_t)(r0 + r) * 128 + c] = acc[i][j][r] + bv;
    }
  }
}

// ---------------------------------------------------------------------------
// Fused attention v6 (R5): 512 thr = 8 waves x 16 q-rows, kv-tile = 32.
// LDS = Ksl 16KB + Vtl 16KB + Ps 8KB = 40KB -> 3-4 blocks/CU (was 2 @ 80KB).
// Rationale: R0 (8w) == R1 (4w, half LDS traffic) == 108us at 2 blocks/CU ->
// per-CU throughput/latency limit that only MORE INDEPENDENT BLOCKS can fill
// (waves within a block are barrier-locked; blocks provide phase diversity).
// Ps swizzle re-derived for 32-wide rows: XOR key col>>2 (<=2-way both phases).
// No setprio (R3), no bias prefetch (R4 spills); plain R0-style scatter bias.
// ---------------------------------------------------------------------------
__global__ __launch_bounds__(512) __attribute__((amdgpu_waves_per_eu(6)))
void attn_fused(const f16* __restrict__ Qp, const f16* __restrict__ Kp,
                const f16* __restrict__ Vp, const float* __restrict__ Bm,
                f16* __restrict__ O) {
  __shared__ f16 Ksl[2][4096];
  __shared__ f16 Vtl[2][4096];
  __shared__ f16 Ps[4096];
  const int tid = threadIdx.x, lane = tid & 63, wid = tid >> 6;  // wid 0..7
  const int col = lane & 15, quad = lane >> 4;
  const int id = blockIdx.x;
  const int mt = (id >> 3) & 7;
  const int bh = ((id >> 6) << 3) | (id & 7);  // 8 m-tiles of one bh per XCD
  const int b = bh >> 3, h = bh & 7;
  const int m0 = mt * 128;
  const int wm = wid * 16;  // wave's 16 q-rows

  const f16* Qb = Qp + (size_t)bh * 131072;
  const f16* Kb = Kp + (size_t)bh * 131072;
  const f16* Vb = Vp + (size_t)bh * 131072;

  // Half-tile t (32 kv): K = contiguous 4KB at Kb + t*4096 (chunks c=0..7);
  // V = chunks (ct*2 + (t&1)) of T-tile t>>1. waves 0-3 K, waves 4-7 V.
#define AISSUE(T, bufi)                                                       \
  {                                                                           \
    if (wid < 4) {                                                            \
      _Pragma("unroll") for (int j = 0; j < 2; j++) {                         \
        const int c = wid * 2 + j;                                            \
        gl_lds16(Kb + (size_t)(T) * 4096 + c * 512 + lane * 8,                \
                 &Ksl[bufi][c * 512]);                                        \
      }                                                                       \
    } else {                                                                  \
      _Pragma("unroll") for (int j = 0; j < 2; j++) {                         \
        const int ct = (wid - 4) * 2 + j;                                     \
        gl_lds16(Vb + (size_t)((T) >> 1) * 8192 +                             \
                     (ct * 2 + ((T) & 1)) * 512 + lane * 8,                   \
                 &Vtl[bufi][ct * 512]);                                       \
      }                                                                       \
    }                                                                         \
  }

  AISSUE(0, 0);
  AISSUE(1, 1);

  f16x8 qf[4];
  {
    const int m = m0 + wm;
    const int T = m >> 6, jt2 = (m >> 4) & 3;
#pragma unroll
    for (int ks = 0; ks < 4; ks++)
      qf[ks] = *(const f16x8*)(Qb + T * 8192 + (jt2 * 4 + ks) * 512 + lane * 8);
  }

  f32x4 oacc[8];
  float l = 0.f;
#pragma unroll
  for (int ct = 0; ct < 8; ct++) oacc[ct] = (f32x4){0.f, 0.f, 0.f, 0.f};

  __syncthreads();

  for (int t = 0; t < 32; ++t) {
    const int buf = t & 1;
    const int n0 = t * 32;

    // bias for this wave's 16 q-rows x 32 kv (scatter: 16 lines/instr)
    float4 breg[2];
    {
      const float* Brow = Bm + (size_t)(m0 + wm + col) * 1024 + n0;
#pragma unroll
      for (int jt = 0; jt < 2; jt++)
        breg[jt] = *(const float4*)(Brow + jt * 16 + quad * 4);
    }

    // QK^T: 8 MFMA; s rows = kv (jt*16 + quad*4 + r), cols = q (col)
    f32x4 s[2];
#pragma unroll
    for (int jt = 0; jt < 2; jt++) s[jt] = (f32x4){0.f, 0.f, 0.f, 0.f};
#pragma unroll
    for (int ks = 0; ks < 4; ks++) {
      f16x8 kf[2];
#pragma unroll
      for (int jt = 0; jt < 2; jt++)
        kf[jt] = *(const f16x8*)&Ksl[buf][(jt * 4 + ks) * 512 + lane * 8];
#pragma unroll
      for (int jt = 0; jt < 2; jt++) s[jt] = MFMA_F16(kf[jt], qf[ks], s[jt]);
    }

    // softmax numerator -> Ps (32-wide rows, XOR-swizzled groups of 8 f16)
    {
      const int m = wm + col;
#pragma unroll
      for (int jt = 0; jt < 2; jt++) {
        const float* bv = (const float*)&breg[jt];
        float p0 = __expf(s[jt][0] + bv[0]);
        float p1 = __expf(s[jt][1] + bv[1]);
        float p2 = __expf(s[jt][2] + bv[2]);
        float p3 = __expf(s[jt][3] + bv[3]);
        l += (p0 + p1) + (p2 + p3);
        f16x4 pk; pk[0] = (f16)p0; pk[1] = (f16)p1; pk[2] = (f16)p2; pk[3] = (f16)p3;
        const int g = (jt * 2 + (quad >> 1)) ^ (col >> 2);
        *(f16x4*)&Ps[m * 32 + g * 8 + (quad & 1) * 4] = pk;
      }
    }

    // PV: lane needs P[q=col][kv=quad*8..+7] at swizzled group quad^(col>>2)
    {
      const int m = wm + col;
      const int g = quad ^ (col >> 2);
      f16x8 pf = *(const f16x8*)&Ps[m * 32 + g * 8];
#pragma unroll
      for (int ct = 0; ct < 8; ct++) {
        f16x8 vf = *(const f16x8*)&Vtl[buf][ct * 512 + lane * 8];
        oacc[ct] = MFMA_F16(pf, vf, oacc[ct]);
      }
    }

    __syncthreads();
    if (t + 2 < 32) AISSUE(t + 2, buf);
  }

  l += __shfl_xor(l, 16);
  l += __shfl_xor(l, 32);
  f16* Ob = O + ((size_t)(b * 1024 + m0 + wm)) * 1024 + h * 128;
#pragma unroll
  for (int r = 0; r < 4; r++) {
    const float lv = __shfl(l, (lane & 48) | (quad * 4 + r));
    const float inv = 1.0f / lv;
#pragma unroll
    for (int ct = 0; ct < 8; ct++)
      Ob[(size_t)(quad * 4 + r) * 1024 + ct * 16 + col] = (f16)(oacc[ct][r] * inv);
  }
}

extern "C" void kernel_launch(void* const* d_in, const int* in_sizes, int n_in,
                              void* d_out, int out_size, void* d_ws, size_t ws_size,
                              hipStream_t stream) {
  (void)in_sizes; (void)n_in; (void)out_size; (void)ws_size;
  const float* x1  = (const float*)d_in[0];
  const float* x2  = (const float*)d_in[1];
  const float* Bm  = (const float*)d_in[2];
  const float* wq  = (const float*)d_in[3];
  const float* wqb = (const float*)d_in[4];
  const float* wk  = (const float*)d_in[5];
  const float* wkb = (const float*)d_in[6];
  const float* wv  = (const float*)d_in[7];
  const float* wvb = (const float*)d_in[8];
  const float* pw  = (const float*)d_in[9];
  const float* pb  = (const float*)d_in[10];
  float* out = (float*)d_out;

  const size_t MiB = 1024 * 1024;
  f16* Qp  = (f16*)d_ws;                            // 0..32 MiB
  f16* Kp  = (f16*)((char*)d_ws + 32 * MiB);        // 32..64
  f16* Vp  = (f16*)((char*)d_ws + 64 * MiB);        // 64..96
  f16* Ow  = (f16*)((char*)d_ws + 96 * MiB);        // 96..128 (attn output)
  // packed inputs: alive only conv->qkv, then overlaid by Ow
  f16* x1p = (f16*)((char*)d_ws + 96 * MiB);        // 8 MiB
  f16* x2p = (f16*)((char*)d_ws + 104 * MiB);       // 8 MiB
  f16* wp  = (f16*)((char*)d_ws + 112 * MiB);       // 1.5 MiB

  const float scale = 0.0883883476483184f;  // 1/sqrt(128)
  conv_pack<<<dim3(280), dim3(256), 0, stream>>>(x1, x2, wq, wk, wv, x1p, x2p, wp);
  gemm_qkv<<<dim3(128, 8, 3), dim3(512), 0, stream>>>(x1p, x2p, wp, wqb, wkb, wvb,
                                                      Qp, Kp, Vp, scale);
  attn_fused<<<dim3(1024), dim3(512), 0, stream>>>(Qp, Kp, Vp, Bm, Ow);
  gemm_proj<<<dim3(256, 2), dim3(256), 0, stream>>>(Ow, pw, pb, out);
}

// Round 7
// 315.612 us; speedup vs baseline: 1.3418x; 1.2811x over previous
//
#include <hip/hip_runtime.h>
#include <hip/hip_fp16.h>

typedef _Float16 f16;
typedef __attribute__((ext_vector_type(4))) _Float16 f16x4;
typedef __attribute__((ext_vector_type(8))) _Float16 f16x8;
typedef __attribute__((ext_vector_type(4))) float f32x4;

#define MFMA_F16(a,b,c) __builtin_amdgcn_mfma_f32_16x16x32_f16((a),(b),(c),0,0,0)

// async 16B/lane global->LDS DMA; global addr per-lane, LDS base wave-uniform
__device__ __forceinline__ void gl_lds16(const f16* g, f16* l) {
  __builtin_amdgcn_global_load_lds(
      (const __attribute__((address_space(1))) unsigned int*)g,
      (__attribute__((address_space(3))) unsigned int*)l, 16, 0, 0);
}

// ---------------------------------------------------------------------------
// Fragment-chunk packing (all DMA-ready, 1KB contiguous chunks):
//  input pack (x/W, [rows][256]): per 128-row tile, chunk (rt,ks8) idx rt*8+ks8
//  Q/K workspace (per b,h; 16 T-tiles of 64 seq x 128 k): chunk (jt,ks) idx
//    jt*4+ks: lane(q,c): [seq=T*64+jt*16+c][k=ks*32+q*8]
//  V workspace: chunk (ct,ks2) idx ct*2+ks2: lane(q,c): [d=ct*16+c][kv=T*64+ks2*32+q*8]
// HISTORY:
//  R3: setprio in lockstep attn: -37%. R4: macro-unrolled bias ping-pong:
//   scratch spills. R6: kv-32 + 3-4 blocks/CU: occupancy 57% but 245us,
//   FETCH 82->208MB -> TLP refuted; cache thrash confirmed.
//  LAW (R0/R1/R6): attn time ~ per-block iteration count; per-iter latency
//   ~8100cy/CU, ~2x any bottom-up model. R7: restore R1 (108us) + noDMA
//   probe dispatch to bisect {staging/HBM} vs {compute chain} share.
//   probe_time = dur_total - 277 (non-attn cost stable at 169us).
// ---------------------------------------------------------------------------

// ---------------------------------------------------------------------------
// Pack pass: fp32 row-major -> f16 fragment-chunk tiles (coalesced in+out).
// ---------------------------------------------------------------------------
__global__ __launch_bounds__(256) void conv_pack(
    const float* __restrict__ x1, const float* __restrict__ x2,
    const float* __restrict__ wq, const float* __restrict__ wk,
    const float* __restrict__ wv,
    f16* __restrict__ x1p, f16* __restrict__ x2p, f16* __restrict__ wp) {
  __shared__ f16 S[128][264];
  const int id = blockIdx.x, tid = threadIdx.x;
  const float* src;
  f16* dst;
  if (id < 128) {
    src = x1 + (size_t)id * 32768; dst = x1p + (size_t)id * 32768;
  } else if (id < 256) {
    src = x2 + (size_t)(id - 128) * 32768; dst = x2p + (size_t)(id - 128) * 32768;
  } else {
    const int wsel = (id - 256) >> 3, wt = (id - 256) & 7;
    const float* wsrc = (wsel == 0) ? wq : (wsel == 1) ? wk : wv;
    src = wsrc + (size_t)wt * 32768;
    dst = wp + (size_t)wsel * 262144 + (size_t)wt * 32768;
  }
#pragma unroll 8
  for (int i = 0; i < 32; i++) {
    int f = i * 256 + tid;           // 8192 float4s = 128 rows x 64
    int row = f >> 6, c4 = f & 63;
    float4 v = *(const float4*)(src + (size_t)row * 256 + c4 * 4);
    f16x4 hh; hh[0] = (f16)v.x; hh[1] = (f16)v.y; hh[2] = (f16)v.z; hh[3] = (f16)v.w;
    *(f16x4*)&S[row][c4 * 4] = hh;
  }
  __syncthreads();
#pragma unroll 8
  for (int i = 0; i < 16; i++) {
    int u = i * 256 + tid;           // 4096 b128 units
    int chunk = u >> 6, l2 = u & 63;
    int q = l2 >> 4, c = l2 & 15;
    int row = (chunk >> 3) * 16 + c, k = (chunk & 7) * 32 + q * 8;
    f16x8 v = *(const f16x8*)&S[row][k];
    *(f16x8*)(dst + (size_t)u * 8) = v;
  }
}

// ---------------------------------------------------------------------------
// QKV GEMM v4: pure-DMA staging. grid (128 xt, 8 h, 3 z). BM=128 x BN=128 x
// BK=64, double-buffered, one barrier/iter. 512 thr = 8 waves.
// ---------------------------------------------------------------------------
__global__ __launch_bounds__(512) __attribute__((amdgpu_waves_per_eu(4, 4)))
void gemm_qkv(const f16* __restrict__ x1p, const f16* __restrict__ x2p,
              const f16* __restrict__ wp,
              const float* __restrict__ wqb, const float* __restrict__ wkb,
              const float* __restrict__ wvb,
              f16* __restrict__ Qp, f16* __restrict__ Kp, f16* __restrict__ Vp,
              float qscale) {
  __shared__ f16 Wl[2][8192];
  __shared__ f16 Xl[2][8192];
  const int z = blockIdx.z;
  const f16* Xp = (z == 0) ? x1p : x2p;
  const float* bias = (z == 0) ? wqb : (z == 1) ? wkb : wvb;
  f16* outp = (z == 0) ? Qp : (z == 1) ? Kp : Vp;
  const float sc = (z == 0) ? qscale : 1.0f;

  const int tid = threadIdx.x, lane = tid & 63, wid = tid >> 6;
  const int col = lane & 15, quad = lane >> 4;
  const int xt = blockIdx.x, h = blockIdx.y;
  const int wr = wid >> 2, xc = wid & 3;  // wave M-group / N-group
  const f16* Xb = Xp + (size_t)xt * 32768;
  const f16* Wb = wp + (size_t)z * 262144 + (size_t)h * 32768;

#define QISSUE(T, bufi)                                                   \
  {                                                                       \
    _Pragma("unroll") for (int j = 0; j < 2; j++) {                       \
      int lc = wid * 2 + j;                                               \
      int rt = lc >> 1, ksl = lc & 1;                                     \
      gl_lds16(Wb + (size_t)((rt * 8 + (T) * 2 + ksl) << 9) + lane * 8,   \
               &Wl[bufi][lc * 512]);                                      \
      gl_lds16(Xb + (size_t)((rt * 8 + (T) * 2 + ksl) << 9) + lane * 8,   \
               &Xl[bufi][lc * 512]);                                      \
    }                                                                     \
  }

  QISSUE(0, 0);
  QISSUE(1, 1);

  f32x4 acc[4][2];
#pragma unroll
  for (int i = 0; i < 4; i++)
#pragma unroll
    for (int j = 0; j < 2; j++) acc[i][j] = (f32x4){0.f, 0.f, 0.f, 0.f};

  __syncthreads();

  for (int t = 0; t < 4; ++t) {
    const int buf = t & 1;
    const f16* Ra = (z == 2) ? Xl[buf] : Wl[buf];  // A-operand (C rows)
    const f16* Cb = (z == 2) ? Wl[buf] : Xl[buf];  // B-operand (C cols)
#pragma unroll
    for (int ksl = 0; ksl < 2; ksl++) {
      f16x8 af[4], bf[2];
#pragma unroll
      for (int i = 0; i < 4; i++)
        af[i] = *(const f16x8*)&Ra[((wr * 4 + i) * 2 + ksl) * 512 + lane * 8];
#pragma unroll
      for (int j = 0; j < 2; j++)
        bf[j] = *(const f16x8*)&Cb[((xc * 2 + j) * 2 + ksl) * 512 + lane * 8];
#pragma unroll
      for (int i = 0; i < 4; i++)
#pragma unroll
        for (int j = 0; j < 2; j++) acc[i][j] = MFMA_F16(af[i], bf[j], acc[i][j]);
    }
    __syncthreads();
    if (t + 2 < 4) QISSUE(t + 2, buf);
  }

  if (z < 2) {
#pragma unroll
    for (int i = 0; i < 4; i++) {
      const int k0h = wr * 64 + i * 16 + quad * 4;
      float4 bq = *(const float4*)(bias + h * 128 + k0h);
      const int ks2 = k0h >> 5, q2 = (k0h >> 3) & 3, lo = k0h & 7;
#pragma unroll
      for (int j = 0; j < 2; j++) {
        const int bn2 = xt * 128 + xc * 32 + j * 16 + col;
        const int b = bn2 >> 10, n2 = bn2 & 1023;
        const int T = n2 >> 6, jt = (n2 >> 4) & 3, c2 = n2 & 15;
        f16x4 pk;
#pragma unroll
        for (int r = 0; r < 4; r++)
          pk[r] = (f16)((acc[i][j][r] + ((const float*)&bq)[r]) * sc);
        *(f16x4*)(outp + (size_t)(b * 8 + h) * 131072 + T * 8192 +
                  (jt * 4 + ks2) * 512 + (q2 * 16 + c2) * 8 + lo) = pk;
      }
    }
  } else {
#pragma unroll
    for (int j = 0; j < 2; j++) {
      const int d = xc * 32 + j * 16 + col;
      const float bv = bias[h * 128 + d];
      const int ct = d >> 4, cc = d & 15;
#pragma unroll
      for (int i = 0; i < 4; i++) {
        const int bn2 = xt * 128 + wr * 64 + i * 16 + quad * 4;
        const int b = bn2 >> 10, n2 = bn2 & 1023;
        const int T = n2 >> 6, kv6 = n2 & 63;
        const int ks2 = kv6 >> 5, qv = (kv6 >> 3) & 3, jj = kv6 & 7;
        f16x4 pk;
#pragma unroll
        for (int r = 0; r < 4; r++) pk[r] = (f16)(acc[i][j][r] + bv);
        *(f16x4*)(outp + (size_t)(b * 8 + h) * 131072 + T * 8192 +
                  (ct * 2 + ks2) * 512 + (qv * 16 + cc) * 8 + jj) = pk;
      }
    }
  }
}

// ---------------------------------------------------------------------------
// Proj GEMM: out[16384,128] = A[16384,1024](f16) @ W[128,1024]^T + b, fp32.
// ---------------------------------------------------------------------------
__global__ __launch_bounds__(256) void gemm_proj(const f16* __restrict__ A,
                                                 const float* __restrict__ W,
                                                 const float* __restrict__ bias,
                                                 float* __restrict__ out) {
  constexpr int LD = 72;
  __shared__ f16 As[64][LD];
  __shared__ f16 Bs[64][LD];
  const int tid = threadIdx.x, lane = tid & 63, wid = tid >> 6;
  const int col = lane & 15, quad = lane >> 4;
  const int wm = (wid >> 1) * 32, wn = (wid & 1) * 32;
  const int m0 = blockIdx.x * 64, n0 = blockIdx.y * 64;

  f32x4 acc[2][2];
#pragma unroll
  for (int i = 0; i < 2; i++)
#pragma unroll
    for (int j = 0; j < 2; j++) acc[i][j] = (f32x4){0.f, 0.f, 0.f, 0.f};

  for (int kt = 0; kt < 16; ++kt) {
    const int k0 = kt * 64;
#pragma unroll
    for (int i = 0; i < 2; i++) {
      int f = i * 256 + tid;
      int r = f >> 3, ch = f & 7;
      *(f16x8*)&As[r][ch * 8] = *(const f16x8*)(A + (size_t)(m0 + r) * 1024 + k0 + ch * 8);
    }
#pragma unroll
    for (int i = 0; i < 4; i++) {
      int f = i * 256 + tid;
      int r = f >> 4, c4 = f & 15;
      float4 v = *(const float4*)(W + (size_t)(n0 + r) * 1024 + k0 + c4 * 4);
      f16x4 hh; hh[0] = (f16)v.x; hh[1] = (f16)v.y; hh[2] = (f16)v.z; hh[3] = (f16)v.w;
      *(f16x4*)&Bs[r][c4 * 4] = hh;
    }
    __syncthreads();
#pragma unroll
    for (int ks = 0; ks < 2; ks++) {
      f16x8 af[2], bf[2];
#pragma unroll
      for (int i = 0; i < 2; i++) af[i] = *(const f16x8*)&As[wm + i * 16 + col][ks * 32 + quad * 8];
#pragma unroll
      for (int j = 0; j < 2; j++) bf[j] = *(const f16x8*)&Bs[wn + j * 16 + col][ks * 32 + quad * 8];
#pragma unroll
      for (int i = 0; i < 2; i++)
#pragma unroll
        for (int j = 0; j < 2; j++) acc[i][j] = MFMA_F16(af[i], bf[j], acc[i][j]);
    }
    __syncthreads();
  }
#pragma unroll
  for (int j = 0; j < 2; j++) {
    const int c = n0 + wn + j * 16 + col;
    const float bv = bias[c];
#pragma unroll
    for (int i = 0; i < 2; i++) {
      const int r0 = m0 + wm + i * 16 + quad * 4;
#pragma unroll
      for (int r = 0; r < 4; r++)
        out[(size_t)(r0 + r) * 128 + c] = acc[i][j][r] + bv;
    }
  }
}

// ---------------------------------------------------------------------------
// Fused attention (R1-verified, 108us): 256 thr = 4 waves x 32 q-rows,
// kv-tile 64, double-buffered DMA, one barrier/iter. LDS 80KB -> 2 blocks/CU.
// ---------------------------------------------------------------------------
__global__ __launch_bounds__(256, 2)
void attn_fused(const f16* __restrict__ Qp, const f16* __restrict__ Kp,
                const f16* __restrict__ Vp, const float* __restrict__ Bm,
                f16* __restrict__ O) {
  __shared__ f16 Ksl[2][8192];
  __shared__ f16 Vtl[2][8192];
  __shared__ f16 Ps[8192];
  const int tid = threadIdx.x, lane = tid & 63, wid = tid >> 6;  // wid 0..3
  const int col = lane & 15, quad = lane >> 4;
  const int id = blockIdx.x;
  const int mt = (id >> 3) & 7;
  const int bh = ((id >> 6) << 3) | (id & 7);
  const int b = bh >> 3, h = bh & 7;
  const int m0 = mt * 128;
  const int wm = wid * 32;

  const f16* Qb = Qp + (size_t)bh * 131072;
  const f16* Kb = Kp + (size_t)bh * 131072;
  const f16* Vb = Vp + (size_t)bh * 131072;

#define AISSUE(T, bufi)                                                       \
  {                                                                           \
    if (wid < 2) {                                                            \
      _Pragma("unroll") for (int j = 0; j < 8; j++)                           \
          gl_lds16(Kb + (size_t)(T) * 8192 + (wid * 8 + j) * 512 + lane * 8,  \
                   &Ksl[bufi][(wid * 8 + j) * 512]);                          \
    } else {                                                                  \
      _Pragma("unroll") for (int j = 0; j < 8; j++)                           \
          gl_lds16(Vb + (size_t)(T) * 8192 + ((wid - 2) * 8 + j) * 512 + lane * 8, \
                   &Vtl[bufi][((wid - 2) * 8 + j) * 512]);                    \
    }                                                                         \
  }

  AISSUE(0, 0);
  AISSUE(1, 1);

  f16x8 qf[2][4];
#pragma unroll
  for (int qc = 0; qc < 2; qc++) {
    const int m = m0 + wm + qc * 16;
    const int T = m >> 6, jt2 = (m >> 4) & 3;
#pragma unroll
    for (int ks = 0; ks < 4; ks++)
      qf[qc][ks] = *(const f16x8*)(Qb + T * 8192 + (jt2 * 4 + ks) * 512 + lane * 8);
  }

  f32x4 oacc[2][8];
  float l[2] = {0.f, 0.f};
#pragma unroll
  for (int qc = 0; qc < 2; qc++)
#pragma unroll
    for (int ct = 0; ct < 8; ct++) oacc[qc][ct] = (f32x4){0.f, 0.f, 0.f, 0.f};

  __syncthreads();

  for (int t = 0; t < 16; ++t) {
    const int buf = t & 1;
    const int n0 = t * 64;

    float4 breg[2][4];
#pragma unroll
    for (int qc = 0; qc < 2; qc++) {
      const float* Brow = Bm + (size_t)(m0 + wm + qc * 16 + col) * 1024 + n0;
#pragma unroll
      for (int jt = 0; jt < 4; jt++)
        breg[qc][jt] = *(const float4*)(Brow + jt * 16 + quad * 4);
    }

    f32x4 s[2][4];
#pragma unroll
    for (int qc = 0; qc < 2; qc++)
#pragma unroll
      for (int jt = 0; jt < 4; jt++) s[qc][jt] = (f32x4){0.f, 0.f, 0.f, 0.f};
#pragma unroll
    for (int ks = 0; ks < 4; ks++) {
      f16x8 kf[4];
#pragma unroll
      for (int jt = 0; jt < 4; jt++)
        kf[jt] = *(const f16x8*)&Ksl[buf][(jt * 4 + ks) * 512 + lane * 8];
#pragma unroll
      for (int jt = 0; jt < 4; jt++)
#pragma unroll
        for (int qc = 0; qc < 2; qc++)
          s[qc][jt] = MFMA_F16(kf[jt], qf[qc][ks], s[qc][jt]);
    }

#pragma unroll
    for (int qc = 0; qc < 2; qc++) {
      const int m = wm + qc * 16 + col;
#pragma unroll
      for (int jt = 0; jt < 4; jt++) {
        const float* bv = (const float*)&breg[qc][jt];
        float p0 = __expf(s[qc][jt][0] + bv[0]);
        float p1 = __expf(s[qc][jt][1] + bv[1]);
        float p2 = __expf(s[qc][jt][2] + bv[2]);
        float p3 = __expf(s[qc][jt][3] + bv[3]);
        l[qc] += (p0 + p1) + (p2 + p3);
        f16x4 pk; pk[0] = (f16)p0; pk[1] = (f16)p1; pk[2] = (f16)p2; pk[3] = (f16)p3;
        const int g = (jt * 2 + (quad >> 1)) ^ (col & 7);
        *(f16x4*)&Ps[m * 64 + g * 8 + (quad & 1) * 4] = pk;
      }
    }

#pragma unroll
    for (int ks = 0; ks < 2; ks++) {
      f16x8 pf[2];
#pragma unroll
      for (int qc = 0; qc < 2; qc++) {
        const int m = wm + qc * 16 + col;
        const int g = (ks * 4 + quad) ^ (col & 7);
        pf[qc] = *(const f16x8*)&Ps[m * 64 + g * 8];
      }
#pragma unroll
      for (int ct = 0; ct < 8; ct++) {
        f16x8 vf = *(const f16x8*)&Vtl[buf][(ct * 2 + ks) * 512 + lane * 8];
#pragma unroll
        for (int qc = 0; qc < 2; qc++)
          oacc[qc][ct] = MFMA_F16(pf[qc], vf, oacc[qc][ct]);
      }
    }

    __syncthreads();
    if (t + 2 < 16) AISSUE(t + 2, buf);
  }

#pragma unroll
  for (int qc = 0; qc < 2; qc++) {
    float lw = l[qc];
    lw += __shfl_xor(lw, 16);
    lw += __shfl_xor(lw, 32);
    f16* Ob = O + ((size_t)(b * 1024 + m0 + wm + qc * 16)) * 1024 + h * 128;
#pragma unroll
    for (int r = 0; r < 4; r++) {
      const float lv = __shfl(lw, (lane & 48) | (quad * 4 + r));
      const float inv = 1.0f / lv;
#pragma unroll
      for (int ct = 0; ct < 8; ct++)
        Ob[(size_t)(quad * 4 + r) * 1024 + ct * 16 + col] = (f16)(oacc[qc][ct][r] * inv);
    }
  }
}

// ---------------------------------------------------------------------------
// DIAGNOSTIC PROBE (noDMA): attn_fused verbatim MINUS all global_load_lds
// staging (kf/vf read stale/uninit LDS; numerically garbage, never consumed).
// Writes into the dead Qp region (races harmless). Grid 512 = one block-round.
// probe_time = dur_total - 277; full pipeline would be ~54us at this grid.
// If probe << 54: staging/HBM owns the per-iter idle. If ~54: compute chain.
// ---------------------------------------------------------------------------
__global__ __launch_bounds__(256, 2)
void attn_probe(const f16* __restrict__ Qp, const f16* __restrict__ Kp,
                const f16* __restrict__ Vp, const float* __restrict__ Bm,
                f16* __restrict__ Oscrap) {
  __shared__ f16 Ksl[2][8192];
  __shared__ f16 Vtl[2][8192];
  __shared__ f16 Ps[8192];
  const int tid = threadIdx.x, lane = tid & 63, wid = tid >> 6;
  const int col = lane & 15, quad = lane >> 4;
  const int id = blockIdx.x;
  const int mt = (id >> 3) & 7;
  const int bh = ((id >> 6) << 3) | (id & 7);
  const int b = bh >> 3, h = bh & 7;
  const int m0 = mt * 128;
  const int wm = wid * 32;

  const f16* Qb = Qp + (size_t)bh * 131072;
  (void)Kp; (void)Vp;  // staging removed — the probe's single delta vs attn_fused

  f16x8 qf[2][4];
#pragma unroll
  for (int qc = 0; qc < 2; qc++) {
    const int m = m0 + wm + qc * 16;
    const int T = m >> 6, jt2 = (m >> 4) & 3;
#pragma unroll
    for (int ks = 0; ks < 4; ks++)
      qf[qc][ks] = *(const f16x8*)(Qb + T * 8192 + (jt2 * 4 + ks) * 512 + lane * 8);
  }

  f32x4 oacc[2][8];
  float l[2] = {0.f, 0.f};
#pragma unroll
  for (int qc = 0; qc < 2; qc++)
#pragma unroll
    for (int ct = 0; ct < 8; ct++) oacc[qc][ct] = (f32x4){0.f, 0.f, 0.f, 0.f};

  __syncthreads();

  for (int t = 0; t < 16; ++t) {
    const int buf = t & 1;
    const int n0 = t * 64;

    float4 breg[2][4];
#pragma unroll
    for (int qc = 0; qc < 2; qc++) {
      const float* Brow = Bm + (size_t)(m0 + wm + qc * 16 + col) * 1024 + n0;
#pragma unroll
      for (int jt = 0; jt < 4; jt++)
        breg[qc][jt] = *(const float4*)(Brow + jt * 16 + quad * 4);
    }

    f32x4 s[2][4];
#pragma unroll
    for (int qc = 0; qc < 2; qc++)
#pragma unroll
      for (int jt = 0; jt < 4; jt++) s[qc][jt] = (f32x4){0.f, 0.f, 0.f, 0.f};
#pragma unroll
    for (int ks = 0; ks < 4; ks++) {
      f16x8 kf[4];
#pragma unroll
      for (int jt = 0; jt < 4; jt++)
        kf[jt] = *(const f16x8*)&Ksl[buf][(jt * 4 + ks) * 512 + lane * 8];
#pragma unroll
      for (int jt = 0; jt < 4; jt++)
#pragma unroll
        for (int qc = 0; qc < 2; qc++)
          s[qc][jt] = MFMA_F16(kf[jt], qf[qc][ks], s[qc][jt]);
    }

#pragma unroll
    for (int qc = 0; qc < 2; qc++) {
      const int m = wm + qc * 16 + col;
#pragma unroll
      for (int jt = 0; jt < 4; jt++) {
        const float* bv = (const float*)&breg[qc][jt];
        float p0 = __expf(s[qc][jt][0] + bv[0]);
        float p1 = __expf(s[qc][jt][1] + bv[1]);
        float p2 = __expf(s[qc][jt][2] + bv[2]);
        float p3 = __expf(s[qc][jt][3] + bv[3]);
        l[qc] += (p0 + p1) + (p2 + p3);
        f16x4 pk; pk[0] = (f16)p0; pk[1] = (f16)p1; pk[2] = (f16)p2; pk[3] = (f16)p3;
        const int g = (jt * 2 + (quad >> 1)) ^ (col & 7);
        *(f16x4*)&Ps[m * 64 + g * 8 + (quad & 1) * 4] = pk;
      }
    }

#pragma unroll
    for (int ks = 0; ks < 2; ks++) {
      f16x8 pf[2];
#pragma unroll
      for (int qc = 0; qc < 2; qc++) {
        const int m = wm + qc * 16 + col;
        const int g = (ks * 4 + quad) ^ (col & 7);
        pf[qc] = *(const f16x8*)&Ps[m * 64 + g * 8];
      }
#pragma unroll
      for (int ct = 0; ct < 8; ct++) {
        f16x8 vf = *(const f16x8*)&Vtl[buf][(ct * 2 + ks) * 512 + lane * 8];
#pragma unroll
        for (int qc = 0; qc < 2; qc++)
          oacc[qc][ct] = MFMA_F16(pf[qc], vf, oacc[qc][ct]);
      }
    }

    __syncthreads();
    // (no AISSUE — this is the probe's ablation)
  }

#pragma unroll
  for (int qc = 0; qc < 2; qc++) {
    float lw = l[qc];
    lw += __shfl_xor(lw, 16);
    lw += __shfl_xor(lw, 32);
    f16* Ob = Oscrap + ((size_t)(b * 1024 + m0 + wm + qc * 16)) * 1024 + h * 128;
#pragma unroll
    for (int r = 0; r < 4; r++) {
      const float lv = __shfl(lw, (lane & 48) | (quad * 4 + r));
      const float inv = 1.0f / lv;
#pragma unroll
      for (int ct = 0; ct < 8; ct++)
        Ob[(size_t)(quad * 4 + r) * 1024 + ct * 16 + col] = (f16)(oacc[qc][ct][r] * inv);
    }
  }
}

extern "C" void kernel_launch(void* const* d_in, const int* in_sizes, int n_in,
                              void* d_out, int out_size, void* d_ws, size_t ws_size,
                              hipStream_t stream) {
  (void)in_sizes; (void)n_in; (void)out_size; (void)ws_size;
  const float* x1  = (const float*)d_in[0];
  const float* x2  = (const float*)d_in[1];
  const float* Bm  = (const float*)d_in[2];
  const float* wq  = (const float*)d_in[3];
  const float* wqb = (const float*)d_in[4];
  const float* wk  = (const float*)d_in[5];
  const float* wkb = (const float*)d_in[6];
  const float* wv  = (const float*)d_in[7];
  const float* wvb = (const float*)d_in[8];
  const float* pw  = (const float*)d_in[9];
  const float* pb  = (const float*)d_in[10];
  float* out = (float*)d_out;

  const size_t MiB = 1024 * 1024;
  f16* Qp  = (f16*)d_ws;                            // 0..32 MiB
  f16* Kp  = (f16*)((char*)d_ws + 32 * MiB);        // 32..64
  f16* Vp  = (f16*)((char*)d_ws + 64 * MiB);        // 64..96
  f16* Ow  = (f16*)((char*)d_ws + 96 * MiB);        // 96..128 (attn output)
  // packed inputs: alive only conv->qkv, then overlaid by Ow
  f16* x1p = (f16*)((char*)d_ws + 96 * MiB);        // 8 MiB
  f16* x2p = (f16*)((char*)d_ws + 104 * MiB);       // 8 MiB
  f16* wp  = (f16*)((char*)d_ws + 112 * MiB);       // 1.5 MiB

  const float scale = 0.0883883476483184f;  // 1/sqrt(128)
  conv_pack<<<dim3(280), dim3(256), 0, stream>>>(x1, x2, wq, wk, wv, x1p, x2p, wp);
  gemm_qkv<<<dim3(128, 8, 3), dim3(512), 0, stream>>>(x1p, x2p, wp, wqb, wkb, wvb,
                                                      Qp, Kp, Vp, scale);
  attn_fused<<<dim3(1024), dim3(256), 0, stream>>>(Qp, Kp, Vp, Bm, Ow);
  // Diagnostic probe: noDMA attn at half grid (one block-round); output goes
  // into the dead Qp region (never read again). probe_time = total - 277us.
  attn_probe<<<dim3(512), dim3(256), 0, stream>>>(Qp, Kp, Vp, Bm, Qp);
  gemm_proj<<<dim3(256, 2), dim3(256), 0, stream>>>(Ow, pw, pb, out);
}

// Round 8
// 276.645 us; speedup vs baseline: 1.5308x; 1.1409x over previous
//
#include <hip/hip_runtime.h>
#include <hip/hip_fp16.h>

typedef _Float16 f16;
typedef __attribute__((ext_vector_type(4))) _Float16 f16x4;
typedef __attribute__((ext_vector_type(8))) _Float16 f16x8;
typedef __attribute__((ext_vector_type(4))) float f32x4;

#define MFMA_F16(a,b,c) __builtin_amdgcn_mfma_f32_16x16x32_f16((a),(b),(c),0,0,0)

// async 16B/lane global->LDS DMA; global addr per-lane, LDS base wave-uniform
__device__ __forceinline__ void gl_lds16(const f16* g, f16* l) {
  __builtin_amdgcn_global_load_lds(
      (const __attribute__((address_space(1))) unsigned int*)g,
      (__attribute__((address_space(3))) unsigned int*)l, 16, 0, 0);
}

// ---------------------------------------------------------------------------
// Fragment-chunk packing (all DMA-ready, 1KB contiguous chunks):
//  input pack (x/W, [rows][256]): per 128-row tile, chunk (rt,ks8) idx rt*8+ks8
//  Q/K workspace (per b,h; 16 T-tiles of 64 seq x 128 k): chunk (jt,ks) idx
//    jt*4+ks: lane(q,c): [seq=T*64+jt*16+c][k=ks*32+q*8]
//  V workspace: chunk (ct,ks2) idx ct*2+ks2: lane(q,c): [d=ct*16+c][kv=T*64+ks2*32+q*8]
// HISTORY:
//  R3 setprio: -37% (lockstep). R4 bias ping-pong: spills. R6 kv-32 hi-occ:
//   -2.3x, FETCH 82->208MB (thrash). R7 noDMA probe: removing global_load_lds
//   staging HALVES per-iter time (8100->4300cy) despite a full iteration of
//   latency slack -> cost is the TCP->LDS DMA path + syncthreads' vmcnt(0)
//   drain, not read latency.
//  R8 (T14): reg-staging. global->reg loads issued mid-iter t for tile t+2
//   (FIFO-ordered after breg so softmax's vmcnt leaves them in flight);
//   ds_write into the freed buffer at top of iter t+1; raw s_barrier with
//   lgkmcnt(0) only -- loads survive the barrier (T4 counted-vmcnt essence).
// ---------------------------------------------------------------------------

// ---------------------------------------------------------------------------
// Pack pass: fp32 row-major -> f16 fragment-chunk tiles (coalesced in+out).
// ---------------------------------------------------------------------------
__global__ __launch_bounds__(256) void conv_pack(
    const float* __restrict__ x1, const float* __restrict__ x2,
    const float* __restrict__ wq, const float* __restrict__ wk,
    const float* __restrict__ wv,
    f16* __restrict__ x1p, f16* __restrict__ x2p, f16* __restrict__ wp) {
  __shared__ f16 S[128][264];
  const int id = blockIdx.x, tid = threadIdx.x;
  const float* src;
  f16* dst;
  if (id < 128) {
    src = x1 + (size_t)id * 32768; dst = x1p + (size_t)id * 32768;
  } else if (id < 256) {
    src = x2 + (size_t)(id - 128) * 32768; dst = x2p + (size_t)(id - 128) * 32768;
  } else {
    const int wsel = (id - 256) >> 3, wt = (id - 256) & 7;
    const float* wsrc = (wsel == 0) ? wq : (wsel == 1) ? wk : wv;
    src = wsrc + (size_t)wt * 32768;
    dst = wp + (size_t)wsel * 262144 + (size_t)wt * 32768;
  }
#pragma unroll 8
  for (int i = 0; i < 32; i++) {
    int f = i * 256 + tid;           // 8192 float4s = 128 rows x 64
    int row = f >> 6, c4 = f & 63;
    float4 v = *(const float4*)(src + (size_t)row * 256 + c4 * 4);
    f16x4 hh; hh[0] = (f16)v.x; hh[1] = (f16)v.y; hh[2] = (f16)v.z; hh[3] = (f16)v.w;
    *(f16x4*)&S[row][c4 * 4] = hh;
  }
  __syncthreads();
#pragma unroll 8
  for (int i = 0; i < 16; i++) {
    int u = i * 256 + tid;           // 4096 b128 units
    int chunk = u >> 6, l2 = u & 63;
    int q = l2 >> 4, c = l2 & 15;
    int row = (chunk >> 3) * 16 + c, k = (chunk & 7) * 32 + q * 8;
    f16x8 v = *(const f16x8*)&S[row][k];
    *(f16x8*)(dst + (size_t)u * 8) = v;
  }
}

// ---------------------------------------------------------------------------
// QKV GEMM v4: pure-DMA staging. grid (128 xt, 8 h, 3 z). BM=128 x BN=128 x
// BK=64, double-buffered, one barrier/iter. 512 thr = 8 waves.
// ---------------------------------------------------------------------------
__global__ __launch_bounds__(512) __attribute__((amdgpu_waves_per_eu(4, 4)))
void gemm_qkv(const f16* __restrict__ x1p, const f16* __restrict__ x2p,
              const f16* __restrict__ wp,
              const float* __restrict__ wqb, const float* __restrict__ wkb,
              const float* __restrict__ wvb,
              f16* __restrict__ Qp, f16* __restrict__ Kp, f16* __restrict__ Vp,
              float qscale) {
  __shared__ f16 Wl[2][8192];
  __shared__ f16 Xl[2][8192];
  const int z = blockIdx.z;
  const f16* Xp = (z == 0) ? x1p : x2p;
  const float* bias = (z == 0) ? wqb : (z == 1) ? wkb : wvb;
  f16* outp = (z == 0) ? Qp : (z == 1) ? Kp : Vp;
  const float sc = (z == 0) ? qscale : 1.0f;

  const int tid = threadIdx.x, lane = tid & 63, wid = tid >> 6;
  const int col = lane & 15, quad = lane >> 4;
  const int xt = blockIdx.x, h = blockIdx.y;
  const int wr = wid >> 2, xc = wid & 3;  // wave M-group / N-group
  const f16* Xb = Xp + (size_t)xt * 32768;
  const f16* Wb = wp + (size_t)z * 262144 + (size_t)h * 32768;

#define QISSUE(T, bufi)                                                   \
  {                                                                       \
    _Pragma("unroll") for (int j = 0; j < 2; j++) {                       \
      int lc = wid * 2 + j;                                               \
      int rt = lc >> 1, ksl = lc & 1;                                     \
      gl_lds16(Wb + (size_t)((rt * 8 + (T) * 2 + ksl) << 9) + lane * 8,   \
               &Wl[bufi][lc * 512]);                                      \
      gl_lds16(Xb + (size_t)((rt * 8 + (T) * 2 + ksl) << 9) + lane * 8,   \
               &Xl[bufi][lc * 512]);                                      \
    }                                                                     \
  }

  QISSUE(0, 0);
  QISSUE(1, 1);

  f32x4 acc[4][2];
#pragma unroll
  for (int i = 0; i < 4; i++)
#pragma unroll
    for (int j = 0; j < 2; j++) acc[i][j] = (f32x4){0.f, 0.f, 0.f, 0.f};

  __syncthreads();

  for (int t = 0; t < 4; ++t) {
    const int buf = t & 1;
    const f16* Ra = (z == 2) ? Xl[buf] : Wl[buf];  // A-operand (C rows)
    const f16* Cb = (z == 2) ? Wl[buf] : Xl[buf];  // B-operand (C cols)
#pragma unroll
    for (int ksl = 0; ksl < 2; ksl++) {
      f16x8 af[4], bf[2];
#pragma unroll
      for (int i = 0; i < 4; i++)
        af[i] = *(const f16x8*)&Ra[((wr * 4 + i) * 2 + ksl) * 512 + lane * 8];
#pragma unroll
      for (int j = 0; j < 2; j++)
        bf[j] = *(const f16x8*)&Cb[((xc * 2 + j) * 2 + ksl) * 512 + lane * 8];
#pragma unroll
      for (int i = 0; i < 4; i++)
#pragma unroll
        for (int j = 0; j < 2; j++) acc[i][j] = MFMA_F16(af[i], bf[j], acc[i][j]);
    }
    __syncthreads();
    if (t + 2 < 4) QISSUE(t + 2, buf);
  }

  if (z < 2) {
#pragma unroll
    for (int i = 0; i < 4; i++) {
      const int k0h = wr * 64 + i * 16 + quad * 4;
      float4 bq = *(const float4*)(bias + h * 128 + k0h);
      const int ks2 = k0h >> 5, q2 = (k0h >> 3) & 3, lo = k0h & 7;
#pragma unroll
      for (int j = 0; j < 2; j++) {
        const int bn2 = xt * 128 + xc * 32 + j * 16 + col;
        const int b = bn2 >> 10, n2 = bn2 & 1023;
        const int T = n2 >> 6, jt = (n2 >> 4) & 3, c2 = n2 & 15;
        f16x4 pk;
#pragma unroll
        for (int r = 0; r < 4; r++)
          pk[r] = (f16)((acc[i][j][r] + ((const float*)&bq)[r]) * sc);
        *(f16x4*)(outp + (size_t)(b * 8 + h) * 131072 + T * 8192 +
                  (jt * 4 + ks2) * 512 + (q2 * 16 + c2) * 8 + lo) = pk;
      }
    }
  } else {
#pragma unroll
    for (int j = 0; j < 2; j++) {
      const int d = xc * 32 + j * 16 + col;
      const float bv = bias[h * 128 + d];
      const int ct = d >> 4, cc = d & 15;
#pragma unroll
      for (int i = 0; i < 4; i++) {
        const int bn2 = xt * 128 + wr * 64 + i * 16 + quad * 4;
        const int b = bn2 >> 10, n2 = bn2 & 1023;
        const int T = n2 >> 6, kv6 = n2 & 63;
        const int ks2 = kv6 >> 5, qv = (kv6 >> 3) & 3, jj = kv6 & 7;
        f16x4 pk;
#pragma unroll
        for (int r = 0; r < 4; r++) pk[r] = (f16)(acc[i][j][r] + bv);
        *(f16x4*)(outp + (size_t)(b * 8 + h) * 131072 + T * 8192 +
                  (ct * 2 + ks2) * 512 + (qv * 16 + cc) * 8 + jj) = pk;
      }
    }
  }
}

// ---------------------------------------------------------------------------
// Proj GEMM: out[16384,128] = A[16384,1024](f16) @ W[128,1024]^T + b, fp32.
// ---------------------------------------------------------------------------
__global__ __launch_bounds__(256) void gemm_proj(const f16* __restrict__ A,
                                                 const float* __restrict__ W,
                                                 const float* __restrict__ bias,
                                                 float* __restrict__ out) {
  constexpr int LD = 72;
  __shared__ f16 As[64][LD];
  __shared__ f16 Bs[64][LD];
  const int tid = threadIdx.x, lane = tid & 63, wid = tid >> 6;
  const int col = lane & 15, quad = lane >> 4;
  const int wm = (wid >> 1) * 32, wn = (wid & 1) * 32;
  const int m0 = blockIdx.x * 64, n0 = blockIdx.y * 64;

  f32x4 acc[2][2];
#pragma unroll
  for (int i = 0; i < 2; i++)
#pragma unroll
    for (int j = 0; j < 2; j++) acc[i][j] = (f32x4){0.f, 0.f, 0.f, 0.f};

  for (int kt = 0; kt < 16; ++kt) {
    const int k0 = kt * 64;
#pragma unroll
    for (int i = 0; i < 2; i++) {
      int f = i * 256 + tid;
      int r = f >> 3, ch = f & 7;
      *(f16x8*)&As[r][ch * 8] = *(const f16x8*)(A + (size_t)(m0 + r) * 1024 + k0 + ch * 8);
    }
#pragma unroll
    for (int i = 0; i < 4; i++) {
      int f = i * 256 + tid;
      int r = f >> 4, c4 = f & 15;
      float4 v = *(const float4*)(W + (size_t)(n0 + r) * 1024 + k0 + c4 * 4);
      f16x4 hh; hh[0] = (f16)v.x; hh[1] = (f16)v.y; hh[2] = (f16)v.z; hh[3] = (f16)v.w;
      *(f16x4*)&Bs[r][c4 * 4] = hh;
    }
    __syncthreads();
#pragma unroll
    for (int ks = 0; ks < 2; ks++) {
      f16x8 af[2], bf[2];
#pragma unroll
      for (int i = 0; i < 2; i++) af[i] = *(const f16x8*)&As[wm + i * 16 + col][ks * 32 + quad * 8];
#pragma unroll
      for (int j = 0; j < 2; j++) bf[j] = *(const f16x8*)&Bs[wn + j * 16 + col][ks * 32 + quad * 8];
#pragma unroll
      for (int i = 0; i < 2; i++)
#pragma unroll
        for (int j = 0; j < 2; j++) acc[i][j] = MFMA_F16(af[i], bf[j], acc[i][j]);
    }
    __syncthreads();
  }
#pragma unroll
  for (int j = 0; j < 2; j++) {
    const int c = n0 + wn + j * 16 + col;
    const float bv = bias[c];
#pragma unroll
    for (int i = 0; i < 2; i++) {
      const int r0 = m0 + wm + i * 16 + quad * 4;
#pragma unroll
      for (int r = 0; r < 4; r++)
        out[(size_t)(r0 + r) * 128 + c] = acc[i][j][r] + bv;
    }
  }
}

// ---------------------------------------------------------------------------
// Fused attention v8 (R8, T14 reg-staging): 256 thr = 4 waves x 32 q-rows,
// kv-tile 64, double-buffered. Staging = global->reg (ALOAD, issued mid-iter
// for t+2, FIFO after breg so softmax's vmcnt leaves them in flight) +
// ds_write (AWRITE, top of iter into the buffer freed by the last barrier).
// Barrier = lgkmcnt(0) + raw s_barrier + sched_barrier(0): NO vmcnt drain --
// in-flight loads cross the barrier (R7 probe: syncthreads' vmcnt(0) + DMA
// path cost ~3800cy/iter = half the kernel).
// ---------------------------------------------------------------------------
__global__ __launch_bounds__(256, 2)
void attn_fused(const f16* __restrict__ Qp, const f16* __restrict__ Kp,
                const f16* __restrict__ Vp, const float* __restrict__ Bm,
                f16* __restrict__ O) {
  __shared__ f16 Ksl[2][8192];
  __shared__ f16 Vtl[2][8192];
  __shared__ f16 Ps[8192];
  const int tid = threadIdx.x, lane = tid & 63, wid = tid >> 6;  // wid 0..3
  const int col = lane & 15, quad = lane >> 4;
  const int id = blockIdx.x;
  const int mt = (id >> 3) & 7;
  const int bh = ((id >> 6) << 3) | (id & 7);
  const int b = bh >> 3, h = bh & 7;
  const int m0 = mt * 128;
  const int wm = wid * 32;

  const f16* Qb = Qp + (size_t)bh * 131072;
  const f16* Kb = Kp + (size_t)bh * 131072;
  const f16* Vb = Vp + (size_t)bh * 131072;

  // Reg-staging: each wave owns K chunks [wid*4..+3] and V chunks [wid*4..+3]
  // of each 64-kv tile (chunk = 512 f16 = one b128 per lane).
  f16x8 stK[4], stV[4];

#define ALOAD(T)                                                              \
  {                                                                           \
    _Pragma("unroll") for (int j = 0; j < 4; j++) {                           \
      stK[j] = *(const f16x8*)(Kb + (size_t)(T) * 8192 + (wid * 4 + j) * 512 + lane * 8); \
      stV[j] = *(const f16x8*)(Vb + (size_t)(T) * 8192 + (wid * 4 + j) * 512 + lane * 8); \
    }                                                                         \
  }

#define AWRITE(bufi)                                                          \
  {                                                                           \
    _Pragma("unroll") for (int j = 0; j < 4; j++) {                           \
      *(f16x8*)&Ksl[bufi][(wid * 4 + j) * 512 + lane * 8] = stK[j];           \
      *(f16x8*)&Vtl[bufi][(wid * 4 + j) * 512 + lane * 8] = stV[j];           \
    }                                                                         \
  }

  // barrier WITHOUT vmcnt drain: lgkm (ds ops) only, then raw barrier.
#define ABARRIER()                                                            \
  {                                                                           \
    asm volatile("s_waitcnt lgkmcnt(0)" ::: "memory");                        \
    __builtin_amdgcn_s_barrier();                                             \
    __builtin_amdgcn_sched_barrier(0);                                        \
  }

  // Prologue: tile 0 staged to LDS; tile 1 loaded to regs.
  ALOAD(0);
  AWRITE(0);   // compiler inserts the vmcnt wait for ALOAD(0) regs
  ALOAD(1);

  f16x8 qf[2][4];
#pragma unroll
  for (int qc = 0; qc < 2; qc++) {
    const int m = m0 + wm + qc * 16;
    const int T = m >> 6, jt2 = (m >> 4) & 3;
#pragma unroll
    for (int ks = 0; ks < 4; ks++)
      qf[qc][ks] = *(const f16x8*)(Qb + T * 8192 + (jt2 * 4 + ks) * 512 + lane * 8);
  }

  f32x4 oacc[2][8];
  float l[2] = {0.f, 0.f};
#pragma unroll
  for (int qc = 0; qc < 2; qc++)
#pragma unroll
    for (int ct = 0; ct < 8; ct++) oacc[qc][ct] = (f32x4){0.f, 0.f, 0.f, 0.f};

  ABARRIER();

  for (int t = 0; t < 16; ++t) {
    const int buf = t & 1;
    const int n0 = t * 64;

    // Write tile t+1 regs into the buffer freed by the last barrier.
    if (t + 1 < 16) AWRITE(buf ^ 1);

    // bias for this iter (issued BEFORE ALOAD so its vmcnt wait at softmax
    // leaves the t+2 loads in flight — FIFO vmcnt)
    float4 breg[2][4];
#pragma unroll
    for (int qc = 0; qc < 2; qc++) {
      const float* Brow = Bm + (size_t)(m0 + wm + qc * 16 + col) * 1024 + n0;
#pragma unroll
      for (int jt = 0; jt < 4; jt++)
        breg[qc][jt] = *(const float4*)(Brow + jt * 16 + quad * 4);
    }

    // Issue global loads for tile t+2 (consumed at AWRITE of iter t+1).
    if (t + 2 < 16) ALOAD(t + 2);

    f32x4 s[2][4];
#pragma unroll
    for (int qc = 0; qc < 2; qc++)
#pragma unroll
      for (int jt = 0; jt < 4; jt++) s[qc][jt] = (f32x4){0.f, 0.f, 0.f, 0.f};
#pragma unroll
    for (int ks = 0; ks < 4; ks++) {
      f16x8 kf[4];
#pragma unroll
      for (int jt = 0; jt < 4; jt++)
        kf[jt] = *(const f16x8*)&Ksl[buf][(jt * 4 + ks) * 512 + lane * 8];
#pragma unroll
      for (int jt = 0; jt < 4; jt++)
#pragma unroll
        for (int qc = 0; qc < 2; qc++)
          s[qc][jt] = MFMA_F16(kf[jt], qf[qc][ks], s[qc][jt]);
    }

#pragma unroll
    for (int qc = 0; qc < 2; qc++) {
      const int m = wm + qc * 16 + col;
#pragma unroll
      for (int jt = 0; jt < 4; jt++) {
        const float* bv = (const float*)&breg[qc][jt];
        float p0 = __expf(s[qc][jt][0] + bv[0]);
        float p1 = __expf(s[qc][jt][1] + bv[1]);
        float p2 = __expf(s[qc][jt][2] + bv[2]);
        float p3 = __expf(s[qc][jt][3] + bv[3]);
        l[qc] += (p0 + p1) + (p2 + p3);
        f16x4 pk; pk[0] = (f16)p0; pk[1] = (f16)p1; pk[2] = (f16)p2; pk[3] = (f16)p3;
        const int g = (jt * 2 + (quad >> 1)) ^ (col & 7);
        *(f16x4*)&Ps[m * 64 + g * 8 + (quad & 1) * 4] = pk;
      }
    }

#pragma unroll
    for (int ks = 0; ks < 2; ks++) {
      f16x8 pf[2];
#pragma unroll
      for (int qc = 0; qc < 2; qc++) {
        const int m = wm + qc * 16 + col;
        const int g = (ks * 4 + quad) ^ (col & 7);
        pf[qc] = *(const f16x8*)&Ps[m * 64 + g * 8];
      }
#pragma unroll
      for (int ct = 0; ct < 8; ct++) {
        f16x8 vf = *(const f16x8*)&Vtl[buf][(ct * 2 + ks) * 512 + lane * 8];
#pragma unroll
        for (int qc = 0; qc < 2; qc++)
          oacc[qc][ct] = MFMA_F16(pf[qc], vf, oacc[qc][ct]);
      }
    }

    ABARRIER();
  }

#pragma unroll
  for (int qc = 0; qc < 2; qc++) {
    float lw = l[qc];
    lw += __shfl_xor(lw, 16);
    lw += __shfl_xor(lw, 32);
    f16* Ob = O + ((size_t)(b * 1024 + m0 + wm + qc * 16)) * 1024 + h * 128;
#pragma unroll
    for (int r = 0; r < 4; r++) {
      const float lv = __shfl(lw, (lane & 48) | (quad * 4 + r));
      const float inv = 1.0f / lv;
#pragma unroll
      for (int ct = 0; ct < 8; ct++)
        Ob[(size_t)(quad * 4 + r) * 1024 + ct * 16 + col] = (f16)(oacc[qc][ct][r] * inv);
    }
  }
}

extern "C" void kernel_launch(void* const* d_in, const int* in_sizes, int n_in,
                              void* d_out, int out_size, void* d_ws, size_t ws_size,
                              hipStream_t stream) {
  (void)in_sizes; (void)n_in; (void)out_size; (void)ws_size;
  const float* x1  = (const float*)d_in[0];
  const float* x2  = (const float*)d_in[1];
  const float* Bm  = (const float*)d_in[2];
  const float* wq  = (const float*)d_in[3];
  const float* wqb = (const float*)d_in[4];
  const float* wk  = (const float*)d_in[5];
  const float* wkb = (const float*)d_in[6];
  const float* wv  = (const float*)d_in[7];
  const float* wvb = (const float*)d_in[8];
  const float* pw  = (const float*)d_in[9];
  const float* pb  = (const float*)d_in[10];
  float* out = (float*)d_out;

  const size_t MiB = 1024 * 1024;
  f16* Qp  = (f16*)d_ws;                            // 0..32 MiB
  f16* Kp  = (f16*)((char*)d_ws + 32 * MiB);        // 32..64
  f16* Vp  = (f16*)((char*)d_ws + 64 * MiB);        // 64..96
  f16* Ow  = (f16*)((char*)d_ws + 96 * MiB);        // 96..128 (attn output)
  // packed inputs: alive only conv->qkv, then overlaid by Ow
  f16* x1p = (f16*)((char*)d_ws + 96 * MiB);        // 8 MiB
  f16* x2p = (f16*)((char*)d_ws + 104 * MiB);       // 8 MiB
  f16* wp  = (f16*)((char*)d_ws + 112 * MiB);       // 1.5 MiB

  const float scale = 0.0883883476483184f;  // 1/sqrt(128)
  conv_pack<<<dim3(280), dim3(256), 0, stream>>>(x1, x2, wq, wk, wv, x1p, x2p, wp);
  gemm_qkv<<<dim3(128, 8, 3), dim3(512), 0, stream>>>(x1p, x2p, wp, wqb, wkb, wvb,
                                                      Qp, Kp, Vp, scale);
  attn_fused<<<dim3(1024), dim3(256), 0, stream>>>(Qp, Kp, Vp, Bm, Ow);
  gemm_proj<<<dim3(256, 2), dim3(256), 0, stream>>>(Ow, pw, pb, out);
}

// Round 9
// 266.049 us; speedup vs baseline: 1.5918x; 1.0398x over previous
//
#include <hip/hip_runtime.h>
#include <hip/hip_fp16.h>

typedef _Float16 f16;
typedef __attribute__((ext_vector_type(4))) _Float16 f16x4;
typedef __attribute__((ext_vector_type(8))) _Float16 f16x8;
typedef __attribute__((ext_vector_type(4))) float f32x4;

#define MFMA_F16(a,b,c) __builtin_amdgcn_mfma_f32_16x16x32_f16((a),(b),(c),0,0,0)

// async 16B/lane global->LDS DMA; global addr per-lane, LDS base wave-uniform
__device__ __forceinline__ void gl_lds16(const f16* g, f16* l) {
  __builtin_amdgcn_global_load_lds(
      (const __attribute__((address_space(1))) unsigned int*)g,
      (__attribute__((address_space(3))) unsigned int*)l, 16, 0, 0);
}

// ---------------------------------------------------------------------------
// Fragment-chunk packing (all DMA-ready, 1KB contiguous chunks):
//  input pack (x/W, [rows][256]): per 128-row tile, chunk (rt,ks8) idx rt*8+ks8
//  Q/K workspace (per b,h; 16 T-tiles of 64 seq x 128 k): chunk (jt,ks) idx
//    jt*4+ks: lane(q,c): [seq=T*64+jt*16+c][k=ks*32+q*8]
//  V workspace: chunk (ct,ks2) idx ct*2+ks2: lane(q,c): [d=ct*16+c][kv=T*64+ks2*32+q*8]
//  Eb pack (pack_eb -> d_out!): f16(exp(B)) fragment-coalesced; per (mt,t)
//    tile, lane-slot (qcw,lane) holds 16 f16 = {jt=0..3, r=0..3} for
//    row=qcw*16+(lane&15), cols t*64+jt*16+(lane>>4)*4+r. Lives in d_out's
//    first 2MB (written pre-attn, read by attn, overwritten by gemm_proj).
// HISTORY:
//  R3 setprio: -37% (lockstep). R4 bias ping-pong: spills. R6 kv-32 hi-occ:
//   2.3x slower (more bytes/CU + L3 spill). R7 noDMA probe: halved.
//   R8 T14 reg-staging: NULL -> mechanism/drain not the cost.
//  LAW: time = VMEM bytes per CU / ~15 B/cy/CU (streaming L1-miss rate).
//   R1: bias 64KB + KV 64KB per CU-iter = 8700cy; probe 64KB = 4300cy.
//  R9: halve bias bytes losslessly: Eb = f16(exp(B)) (relative 5e-4, vs
//   f16(B)'s absolute 4e-3), p = expf(s)*eb. Coalesced f16x8 loads.
// ---------------------------------------------------------------------------

// ---------------------------------------------------------------------------
// Pack pass: fp32 row-major -> f16 fragment-chunk tiles (coalesced in+out).
// ---------------------------------------------------------------------------
__global__ __launch_bounds__(256) void conv_pack(
    const float* __restrict__ x1, const float* __restrict__ x2,
    const float* __restrict__ wq, const float* __restrict__ wk,
    const float* __restrict__ wv,
    f16* __restrict__ x1p, f16* __restrict__ x2p, f16* __restrict__ wp) {
  __shared__ f16 S[128][264];
  const int id = blockIdx.x, tid = threadIdx.x;
  const float* src;
  f16* dst;
  if (id < 128) {
    src = x1 + (size_t)id * 32768; dst = x1p + (size_t)id * 32768;
  } else if (id < 256) {
    src = x2 + (size_t)(id - 128) * 32768; dst = x2p + (size_t)(id - 128) * 32768;
  } else {
    const int wsel = (id - 256) >> 3, wt = (id - 256) & 7;
    const float* wsrc = (wsel == 0) ? wq : (wsel == 1) ? wk : wv;
    src = wsrc + (size_t)wt * 32768;
    dst = wp + (size_t)wsel * 262144 + (size_t)wt * 32768;
  }
#pragma unroll 8
  for (int i = 0; i < 32; i++) {
    int f = i * 256 + tid;           // 8192 float4s = 128 rows x 64
    int row = f >> 6, c4 = f & 63;
    float4 v = *(const float4*)(src + (size_t)row * 256 + c4 * 4);
    f16x4 hh; hh[0] = (f16)v.x; hh[1] = (f16)v.y; hh[2] = (f16)v.z; hh[3] = (f16)v.w;
    *(f16x4*)&S[row][c4 * 4] = hh;
  }
  __syncthreads();
#pragma unroll 8
  for (int i = 0; i < 16; i++) {
    int u = i * 256 + tid;           // 4096 b128 units
    int chunk = u >> 6, l2 = u & 63;
    int q = l2 >> 4, c = l2 & 15;
    int row = (chunk >> 3) * 16 + c, k = (chunk & 7) * 32 + q * 8;
    f16x8 v = *(const f16x8*)&S[row][k];
    *(f16x8*)(dst + (size_t)u * 8) = v;
  }
}

// ---------------------------------------------------------------------------
// Eb pack: Ebp[(id*8+qcw)*64+lane][0..15] = f16(exp(B tile)) in fragment-
// coalesced order. Grid 128 (id = mt*16 + t). Output -> d_out scratch.
// ---------------------------------------------------------------------------
__global__ __launch_bounds__(256) void pack_eb(
    const float* __restrict__ Bm, f16* __restrict__ Ebp) {
  __shared__ float S[128][68];   // +4 pad
  const int id = blockIdx.x, tid = threadIdx.x;
  const int mt = id >> 4, t = id & 15;
  const int m0 = mt * 128, n0 = t * 64;
#pragma unroll
  for (int i = 0; i < 8; i++) {
    int f = i * 256 + tid;         // 2048 float4s = 128 rows x 16
    int r = f >> 4, c4 = f & 15;
    float4 v = *(const float4*)(Bm + (size_t)(m0 + r) * 1024 + n0 + c4 * 4);
    *(float4*)&S[r][c4 * 4] = v;
  }
  __syncthreads();
#pragma unroll
  for (int i = 0; i < 2; i++) {
    int s = i * 256 + tid;         // 512 lane-slots (8 qcw x 64 lanes)
    int qcw = s >> 6, lane = s & 63;
    int col = lane & 15, quad = lane >> 4;
    int row = qcw * 16 + col;
    f16x8 h0, h1;
#pragma unroll
    for (int j = 0; j < 8; j++) {
      int jt = j >> 2, r = j & 3;
      h0[j] = (f16)__expf(S[row][jt * 16 + quad * 4 + r]);
    }
#pragma unroll
    for (int j = 0; j < 8; j++) {
      int jt = 2 + (j >> 2), r = j & 3;
      h1[j] = (f16)__expf(S[row][jt * 16 + quad * 4 + r]);
    }
    f16* out = Ebp + (((size_t)id * 8 + qcw) * 64 + lane) * 16;
    *(f16x8*)out = h0;
    *(f16x8*)(out + 8) = h1;
  }
}

// ---------------------------------------------------------------------------
// QKV GEMM v4: pure-DMA staging. grid (128 xt, 8 h, 3 z). BM=128 x BN=128 x
// BK=64, double-buffered, one barrier/iter. 512 thr = 8 waves.
// ---------------------------------------------------------------------------
__global__ __launch_bounds__(512) __attribute__((amdgpu_waves_per_eu(4, 4)))
void gemm_qkv(const f16* __restrict__ x1p, const f16* __restrict__ x2p,
              const f16* __restrict__ wp,
              const float* __restrict__ wqb, const float* __restrict__ wkb,
              const float* __restrict__ wvb,
              f16* __restrict__ Qp, f16* __restrict__ Kp, f16* __restrict__ Vp,
              float qscale) {
  __shared__ f16 Wl[2][8192];
  __shared__ f16 Xl[2][8192];
  const int z = blockIdx.z;
  const f16* Xp = (z == 0) ? x1p : x2p;
  const float* bias = (z == 0) ? wqb : (z == 1) ? wkb : wvb;
  f16* outp = (z == 0) ? Qp : (z == 1) ? Kp : Vp;
  const float sc = (z == 0) ? qscale : 1.0f;

  const int tid = threadIdx.x, lane = tid & 63, wid = tid >> 6;
  const int col = lane & 15, quad = lane >> 4;
  const int xt = blockIdx.x, h = blockIdx.y;
  const int wr = wid >> 2, xc = wid & 3;  // wave M-group / N-group
  const f16* Xb = Xp + (size_t)xt * 32768;
  const f16* Wb = wp + (size_t)z * 262144 + (size_t)h * 32768;

#define QISSUE(T, bufi)                                                   \
  {                                                                       \
    _Pragma("unroll") for (int j = 0; j < 2; j++) {                       \
      int lc = wid * 2 + j;                                               \
      int rt = lc >> 1, ksl = lc & 1;                                     \
      gl_lds16(Wb + (size_t)((rt * 8 + (T) * 2 + ksl) << 9) + lane * 8,   \
               &Wl[bufi][lc * 512]);                                      \
      gl_lds16(Xb + (size_t)((rt * 8 + (T) * 2 + ksl) << 9) + lane * 8,   \
               &Xl[bufi][lc * 512]);                                      \
    }                                                                     \
  }

  QISSUE(0, 0);
  QISSUE(1, 1);

  f32x4 acc[4][2];
#pragma unroll
  for (int i = 0; i < 4; i++)
#pragma unroll
    for (int j = 0; j < 2; j++) acc[i][j] = (f32x4){0.f, 0.f, 0.f, 0.f};

  __syncthreads();

  for (int t = 0; t < 4; ++t) {
    const int buf = t & 1;
    const f16* Ra = (z == 2) ? Xl[buf] : Wl[buf];  // A-operand (C rows)
    const f16* Cb = (z == 2) ? Wl[buf] : Xl[buf];  // B-operand (C cols)
#pragma unroll
    for (int ksl = 0; ksl < 2; ksl++) {
      f16x8 af[4], bf[2];
#pragma unroll
      for (int i = 0; i < 4; i++)
        af[i] = *(const f16x8*)&Ra[((wr * 4 + i) * 2 + ksl) * 512 + lane * 8];
#pragma unroll
      for (int j = 0; j < 2; j++)
        bf[j] = *(const f16x8*)&Cb[((xc * 2 + j) * 2 + ksl) * 512 + lane * 8];
#pragma unroll
      for (int i = 0; i < 4; i++)
#pragma unroll
        for (int j = 0; j < 2; j++) acc[i][j] = MFMA_F16(af[i], bf[j], acc[i][j]);
    }
    __syncthreads();
    if (t + 2 < 4) QISSUE(t + 2, buf);
  }

  if (z < 2) {
#pragma unroll
    for (int i = 0; i < 4; i++) {
      const int k0h = wr * 64 + i * 16 + quad * 4;
      float4 bq = *(const float4*)(bias + h * 128 + k0h);
      const int ks2 = k0h >> 5, q2 = (k0h >> 3) & 3, lo = k0h & 7;
#pragma unroll
      for (int j = 0; j < 2; j++) {
        const int bn2 = xt * 128 + xc * 32 + j * 16 + col;
        const int b = bn2 >> 10, n2 = bn2 & 1023;
        const int T = n2 >> 6, jt = (n2 >> 4) & 3, c2 = n2 & 15;
        f16x4 pk;
#pragma unroll
        for (int r = 0; r < 4; r++)
          pk[r] = (f16)((acc[i][j][r] + ((const float*)&bq)[r]) * sc);
        *(f16x4*)(outp + (size_t)(b * 8 + h) * 131072 + T * 8192 +
                  (jt * 4 + ks2) * 512 + (q2 * 16 + c2) * 8 + lo) = pk;
      }
    }
  } else {
#pragma unroll
    for (int j = 0; j < 2; j++) {
      const int d = xc * 32 + j * 16 + col;
      const float bv = bias[h * 128 + d];
      const int ct = d >> 4, cc = d & 15;
#pragma unroll
      for (int i = 0; i < 4; i++) {
        const int bn2 = xt * 128 + wr * 64 + i * 16 + quad * 4;
        const int b = bn2 >> 10, n2 = bn2 & 1023;
        const int T = n2 >> 6, kv6 = n2 & 63;
        const int ks2 = kv6 >> 5, qv = (kv6 >> 3) & 3, jj = kv6 & 7;
        f16x4 pk;
#pragma unroll
        for (int r = 0; r < 4; r++) pk[r] = (f16)(acc[i][j][r] + bv);
        *(f16x4*)(outp + (size_t)(b * 8 + h) * 131072 + T * 8192 +
                  (ct * 2 + ks2) * 512 + (qv * 16 + cc) * 8 + jj) = pk;
      }
    }
  }
}

// ---------------------------------------------------------------------------
// Proj GEMM: out[16384,128] = A[16384,1024](f16) @ W[128,1024]^T + b, fp32.
// ---------------------------------------------------------------------------
__global__ __launch_bounds__(256) void gemm_proj(const f16* __restrict__ A,
                                                 const float* __restrict__ W,
                                                 const float* __restrict__ bias,
                                                 float* __restrict__ out) {
  constexpr int LD = 72;
  __shared__ f16 As[64][LD];
  __shared__ f16 Bs[64][LD];
  const int tid = threadIdx.x, lane = tid & 63, wid = tid >> 6;
  const int col = lane & 15, quad = lane >> 4;
  const int wm = (wid >> 1) * 32, wn = (wid & 1) * 32;
  const int m0 = blockIdx.x * 64, n0 = blockIdx.y * 64;

  f32x4 acc[2][2];
#pragma unroll
  for (int i = 0; i < 2; i++)
#pragma unroll
    for (int j = 0; j < 2; j++) acc[i][j] = (f32x4){0.f, 0.f, 0.f, 0.f};

  for (int kt = 0; kt < 16; ++kt) {
    const int k0 = kt * 64;
#pragma unroll
    for (int i = 0; i < 2; i++) {
      int f = i * 256 + tid;
      int r = f >> 3, ch = f & 7;
      *(f16x8*)&As[r][ch * 8] = *(const f16x8*)(A + (size_t)(m0 + r) * 1024 + k0 + ch * 8);
    }
#pragma unroll
    for (int i = 0; i < 4; i++) {
      int f = i * 256 + tid;
      int r = f >> 4, c4 = f & 15;
      float4 v = *(const float4*)(W + (size_t)(n0 + r) * 1024 + k0 + c4 * 4);
      f16x4 hh; hh[0] = (f16)v.x; hh[1] = (f16)v.y; hh[2] = (f16)v.z; hh[3] = (f16)v.w;
      *(f16x4*)&Bs[r][c4 * 4] = hh;
    }
    __syncthreads();
#pragma unroll
    for (int ks = 0; ks < 2; ks++) {
      f16x8 af[2], bf[2];
#pragma unroll
      for (int i = 0; i < 2; i++) af[i] = *(const f16x8*)&As[wm + i * 16 + col][ks * 32 + quad * 8];
#pragma unroll
      for (int j = 0; j < 2; j++) bf[j] = *(const f16x8*)&Bs[wn + j * 16 + col][ks * 32 + quad * 8];
#pragma unroll
      for (int i = 0; i < 2; i++)
#pragma unroll
        for (int j = 0; j < 2; j++) acc[i][j] = MFMA_F16(af[i], bf[j], acc[i][j]);
    }
    __syncthreads();
  }
#pragma unroll
  for (int j = 0; j < 2; j++) {
    const int c = n0 + wn + j * 16 + col;
    const float bv = bias[c];
#pragma unroll
    for (int i = 0; i < 2; i++) {
      const int r0 = m0 + wm + i * 16 + quad * 4;
#pragma unroll
      for (int r = 0; r < 4; r++)
        out[(size_t)(r0 + r) * 128 + c] = acc[i][j][r] + bv;
    }
  }
}

// ---------------------------------------------------------------------------
// Fused attention v9 (R1 structure + packed exp-bias): 256 thr = 4 waves x
// 32 q-rows, kv-tile 64, gl_lds double-buffer, one barrier/iter.
// Bias: p = expf(s) * eb, eb = f16(exp(B)) from fragment-coalesced Ebp.
// Bias VMEM per block-iter: 32KB fp32 scatter -> 16KB f16 coalesced (4x fewer
// instrs, 2x fewer lines+bytes). LDS 80KB -> 2 blocks/CU.
// ---------------------------------------------------------------------------
__global__ __launch_bounds__(256, 2)
void attn_fused(const f16* __restrict__ Qp, const f16* __restrict__ Kp,
                const f16* __restrict__ Vp, const f16* __restrict__ Ebp,
                f16* __restrict__ O) {
  __shared__ f16 Ksl[2][8192];
  __shared__ f16 Vtl[2][8192];
  __shared__ f16 Ps[8192];
  const int tid = threadIdx.x, lane = tid & 63, wid = tid >> 6;  // wid 0..3
  const int col = lane & 15, quad = lane >> 4;
  const int id = blockIdx.x;
  const int mt = (id >> 3) & 7;
  const int bh = ((id >> 6) << 3) | (id & 7);
  const int b = bh >> 3, h = bh & 7;
  const int m0 = mt * 128;
  const int wm = wid * 32;

  const f16* Qb = Qp + (size_t)bh * 131072;
  const f16* Kb = Kp + (size_t)bh * 131072;
  const f16* Vb = Vp + (size_t)bh * 131072;
  // exp-bias base for this wave: tile (mt,t), lane-slot (wid*2+qc, lane)
  const f16* Ebw = Ebp + (((size_t)mt * 16 * 8 + wid * 2) * 64 + lane) * 16;

#define AISSUE(T, bufi)                                                       \
  {                                                                           \
    if (wid < 2) {                                                            \
      _Pragma("unroll") for (int j = 0; j < 8; j++)                           \
          gl_lds16(Kb + (size_t)(T) * 8192 + (wid * 8 + j) * 512 + lane * 8,  \
                   &Ksl[bufi][(wid * 8 + j) * 512]);                          \
    } else {                                                                  \
      _Pragma("unroll") for (int j = 0; j < 8; j++)                           \
          gl_lds16(Vb + (size_t)(T) * 8192 + ((wid - 2) * 8 + j) * 512 + lane * 8, \
                   &Vtl[bufi][((wid - 2) * 8 + j) * 512]);                    \
    }                                                                         \
  }

  AISSUE(0, 0);
  AISSUE(1, 1);

  f16x8 qf[2][4];
#pragma unroll
  for (int qc = 0; qc < 2; qc++) {
    const int m = m0 + wm + qc * 16;
    const int T = m >> 6, jt2 = (m >> 4) & 3;
#pragma unroll
    for (int ks = 0; ks < 4; ks++)
      qf[qc][ks] = *(const f16x8*)(Qb + T * 8192 + (jt2 * 4 + ks) * 512 + lane * 8);
  }

  f32x4 oacc[2][8];
  float l[2] = {0.f, 0.f};
#pragma unroll
  for (int qc = 0; qc < 2; qc++)
#pragma unroll
    for (int ct = 0; ct < 8; ct++) oacc[qc][ct] = (f32x4){0.f, 0.f, 0.f, 0.f};

  __syncthreads();

  for (int t = 0; t < 16; ++t) {
    const int buf = t & 1;

    // exp-bias for this wave's 32 q-rows: 4 coalesced f16x8 loads
    f16x8 ebA[2], ebB[2];
    {
      const f16* Et = Ebw + (size_t)t * (8 * 64 * 16);
      ebA[0] = *(const f16x8*)(Et);
      ebB[0] = *(const f16x8*)(Et + 8);
      ebA[1] = *(const f16x8*)(Et + 1024);   // qc=1: +64 lane-slots
      ebB[1] = *(const f16x8*)(Et + 1032);
    }

    f32x4 s[2][4];
#pragma unroll
    for (int qc = 0; qc < 2; qc++)
#pragma unroll
      for (int jt = 0; jt < 4; jt++) s[qc][jt] = (f32x4){0.f, 0.f, 0.f, 0.f};
#pragma unroll
    for (int ks = 0; ks < 4; ks++) {
      f16x8 kf[4];
#pragma unroll
      for (int jt = 0; jt < 4; jt++)
        kf[jt] = *(const f16x8*)&Ksl[buf][(jt * 4 + ks) * 512 + lane * 8];
#pragma unroll
      for (int jt = 0; jt < 4; jt++)
#pragma unroll
        for (int qc = 0; qc < 2; qc++)
          s[qc][jt] = MFMA_F16(kf[jt], qf[qc][ks], s[qc][jt]);
    }

#pragma unroll
    for (int qc = 0; qc < 2; qc++) {
      const int m = wm + qc * 16 + col;
#pragma unroll
      for (int jt = 0; jt < 4; jt++) {
        float p0, p1, p2, p3;
        if (jt < 2) {
          p0 = __expf(s[qc][jt][0]) * (float)ebA[qc][(jt & 1) * 4 + 0];
          p1 = __expf(s[qc][jt][1]) * (float)ebA[qc][(jt & 1) * 4 + 1];
          p2 = __expf(s[qc][jt][2]) * (float)ebA[qc][(jt & 1) * 4 + 2];
          p3 = __expf(s[qc][jt][3]) * (float)ebA[qc][(jt & 1) * 4 + 3];
        } else {
          p0 = __expf(s[qc][jt][0]) * (float)ebB[qc][(jt & 1) * 4 + 0];
          p1 = __expf(s[qc][jt][1]) * (float)ebB[qc][(jt & 1) * 4 + 1];
          p2 = __expf(s[qc][jt][2]) * (float)ebB[qc][(jt & 1) * 4 + 2];
          p3 = __expf(s[qc][jt][3]) * (float)ebB[qc][(jt & 1) * 4 + 3];
        }
        l[qc] += (p0 + p1) + (p2 + p3);
        f16x4 pk; pk[0] = (f16)p0; pk[1] = (f16)p1; pk[2] = (f16)p2; pk[3] = (f16)p3;
        const int g = (jt * 2 + (quad >> 1)) ^ (col & 7);
        *(f16x4*)&Ps[m * 64 + g * 8 + (quad & 1) * 4] = pk;
      }
    }

#pragma unroll
    for (int ks = 0; ks < 2; ks++) {
      f16x8 pf[2];
#pragma unroll
      for (int qc = 0; qc < 2; qc++) {
        const int m = wm + qc * 16 + col;
        const int g = (ks * 4 + quad) ^ (col & 7);
        pf[qc] = *(const f16x8*)&Ps[m * 64 + g * 8];
      }
#pragma unroll
      for (int ct = 0; ct < 8; ct++) {
        f16x8 vf = *(const f16x8*)&Vtl[buf][(ct * 2 + ks) * 512 + lane * 8];
#pragma unroll
        for (int qc = 0; qc < 2; qc++)
          oacc[qc][ct] = MFMA_F16(pf[qc], vf, oacc[qc][ct]);
      }
    }

    __syncthreads();
    if (t + 2 < 16) AISSUE(t + 2, buf);
  }

#pragma unroll
  for (int qc = 0; qc < 2; qc++) {
    float lw = l[qc];
    lw += __shfl_xor(lw, 16);
    lw += __shfl_xor(lw, 32);
    f16* Ob = O + ((size_t)(b * 1024 + m0 + wm + qc * 16)) * 1024 + h * 128;
#pragma unroll
    for (int r = 0; r < 4; r++) {
      const float lv = __shfl(lw, (lane & 48) | (quad * 4 + r));
      const float inv = 1.0f / lv;
#pragma unroll
      for (int ct = 0; ct < 8; ct++)
        Ob[(size_t)(quad * 4 + r) * 1024 + ct * 16 + col] = (f16)(oacc[qc][ct][r] * inv);
    }
  }
}

extern "C" void kernel_launch(void* const* d_in, const int* in_sizes, int n_in,
                              void* d_out, int out_size, void* d_ws, size_t ws_size,
                              hipStream_t stream) {
  (void)in_sizes; (void)n_in; (void)out_size; (void)ws_size;
  const float* x1  = (const float*)d_in[0];
  const float* x2  = (const float*)d_in[1];
  const float* Bm  = (const float*)d_in[2];
  const float* wq  = (const float*)d_in[3];
  const float* wqb = (const float*)d_in[4];
  const float* wk  = (const float*)d_in[5];
  const float* wkb = (const float*)d_in[6];
  const float* wv  = (const float*)d_in[7];
  const float* wvb = (const float*)d_in[8];
  const float* pw  = (const float*)d_in[9];
  const float* pb  = (const float*)d_in[10];
  float* out = (float*)d_out;

  const size_t MiB = 1024 * 1024;
  f16* Qp  = (f16*)d_ws;                            // 0..32 MiB
  f16* Kp  = (f16*)((char*)d_ws + 32 * MiB);        // 32..64
  f16* Vp  = (f16*)((char*)d_ws + 64 * MiB);        // 64..96
  f16* Ow  = (f16*)((char*)d_ws + 96 * MiB);        // 96..128 (attn output)
  // packed inputs: alive only conv->qkv, then overlaid by Ow
  f16* x1p = (f16*)((char*)d_ws + 96 * MiB);        // 8 MiB
  f16* x2p = (f16*)((char*)d_ws + 104 * MiB);       // 8 MiB
  f16* wp  = (f16*)((char*)d_ws + 112 * MiB);       // 1.5 MiB
  // Packed exp-bias lives in d_out's first 2 MiB (out is 8 MiB fp32):
  // written by pack_eb BEFORE attn, read by attn, overwritten by gemm_proj
  // at the end. No workspace-size gamble, no aliasing with the 128MiB live set.
  f16* Ebp = (f16*)d_out;

  const float scale = 0.0883883476483184f;  // 1/sqrt(128)
  conv_pack<<<dim3(280), dim3(256), 0, stream>>>(x1, x2, wq, wk, wv, x1p, x2p, wp);
  pack_eb<<<dim3(128), dim3(256), 0, stream>>>(Bm, Ebp);
  gemm_qkv<<<dim3(128, 8, 3), dim3(512), 0, stream>>>(x1p, x2p, wp, wqb, wkb, wvb,
                                                      Qp, Kp, Vp, scale);
  attn_fused<<<dim3(1024), dim3(256), 0, stream>>>(Qp, Kp, Vp, Ebp, Ow);
  gemm_proj<<<dim3(256, 2), dim3(256), 0, stream>>>(Ow, pw, pb, out);
}

// Round 12
// 262.390 us; speedup vs baseline: 1.6140x; 1.0139x over previous
//
#include <hip/hip_runtime.h>
#include <hip/hip_fp16.h>

typedef _Float16 f16;
typedef __attribute__((ext_vector_type(4))) _Float16 f16x4;
typedef __attribute__((ext_vector_type(8))) _Float16 f16x8;
typedef __attribute__((ext_vector_type(4))) float f32x4;

#define MFMA_F16(a,b,c) __builtin_amdgcn_mfma_f32_16x16x32_f16((a),(b),(c),0,0,0)

// async 16B/lane global->LDS DMA; global addr per-lane, LDS base wave-uniform
__device__ __forceinline__ void gl_lds16(const f16* g, f16* l) {
  __builtin_amdgcn_global_load_lds(
      (const __attribute__((address_space(1))) unsigned int*)g,
      (__attribute__((address_space(3))) unsigned int*)l, 16, 0, 0);
}

// ---------------------------------------------------------------------------
// Fragment-chunk packing (all DMA-ready, 1KB contiguous chunks):
//  input pack (x/W, [rows][256]): per 128-row tile, chunk (rt,ks8) idx rt*8+ks8
//  Q/K workspace (per b,h; 16 T-tiles of 64 seq x 128 k): chunk (jt,ks) idx
//    jt*4+ks: lane(q,c): [seq=T*64+jt*16+c][k=ks*32+q*8]
//  V workspace: chunk (ct,ks2) idx ct*2+ks2: lane(q,c): [d=ct*16+c][kv=T*64+ks2*32+q*8]
//  Eb pack (pack_eb -> d_out, lane-contiguous layout): f16(exp(B));
//    slab(tile128*16+t, qcw, h) = ((tile*8+qcw)*2+h)*512 + lane*8; value j:
//    jt=h*2+(j>>2), r=j&3, row=qcw*16+(lane&15), col=t*64+(lane>>4)*4+jt*16+r.
// HISTORY:
//  R3 setprio: -37% (lockstep). R4 bias ping-pong: spills. R6 kv-32 hi-occ:
//   2.3x slower. R7 noDMA probe: halved. R8 T14 reg-staging: NULL.
//  LAW (R7/R9-confirmed): attn time ~ VMEM bytes/CU / ~15 B/cy + ~15us floor.
//   R9 (Eb f16): 117 -> 99.7us as predicted by the law.
//  R10: halve K/V re-read amplification: 256 q-rows/block (8 waves x 32 rows,
//   per-wave state identical to R9), grid 512, Ps 32KB -> LDS 96KB ->
//   1 block/CU (still 8 waves/CU). Total VMEM 768 -> 512 MB (-33%).
//  (R10+R11 benches were infra failures — container died twice; audited for
//   kernel-induced death [no divergent barriers / OOB / hang]; 3rd submit.
//   If infra fails again or regresses: fall back to R9, attack Ps roundtrip.)
// ---------------------------------------------------------------------------

// ---------------------------------------------------------------------------
// Pack pass: fp32 row-major -> f16 fragment-chunk tiles (coalesced in+out).
// ---------------------------------------------------------------------------
__global__ __launch_bounds__(256) void conv_pack(
    const float* __restrict__ x1, const float* __restrict__ x2,
    const float* __restrict__ wq, const float* __restrict__ wk,
    const float* __restrict__ wv,
    f16* __restrict__ x1p, f16* __restrict__ x2p, f16* __restrict__ wp) {
  __shared__ f16 S[128][264];
  const int id = blockIdx.x, tid = threadIdx.x;
  const float* src;
  f16* dst;
  if (id < 128) {
    src = x1 + (size_t)id * 32768; dst = x1p + (size_t)id * 32768;
  } else if (id < 256) {
    src = x2 + (size_t)(id - 128) * 32768; dst = x2p + (size_t)(id - 128) * 32768;
  } else {
    const int wsel = (id - 256) >> 3, wt = (id - 256) & 7;
    const float* wsrc = (wsel == 0) ? wq : (wsel == 1) ? wk : wv;
    src = wsrc + (size_t)wt * 32768;
    dst = wp + (size_t)wsel * 262144 + (size_t)wt * 32768;
  }
#pragma unroll 8
  for (int i = 0; i < 32; i++) {
    int f = i * 256 + tid;           // 8192 float4s = 128 rows x 64
    int row = f >> 6, c4 = f & 63;
    float4 v = *(const float4*)(src + (size_t)row * 256 + c4 * 4);
    f16x4 hh; hh[0] = (f16)v.x; hh[1] = (f16)v.y; hh[2] = (f16)v.z; hh[3] = (f16)v.w;
    *(f16x4*)&S[row][c4 * 4] = hh;
  }
  __syncthreads();
#pragma unroll 8
  for (int i = 0; i < 16; i++) {
    int u = i * 256 + tid;           // 4096 b128 units
    int chunk = u >> 6, l2 = u & 63;
    int q = l2 >> 4, c = l2 & 15;
    int row = (chunk >> 3) * 16 + c, k = (chunk & 7) * 32 + q * 8;
    f16x8 v = *(const f16x8*)&S[row][k];
    *(f16x8*)(dst + (size_t)u * 8) = v;
  }
}

// ---------------------------------------------------------------------------
// Eb pack: f16(exp(B)) in lane-contiguous fragment order (see header).
// Grid 128 (id = mt128*16 + t). Output -> d_out scratch (2 MiB).
// ---------------------------------------------------------------------------
__global__ __launch_bounds__(256) void pack_eb(
    const float* __restrict__ Bm, f16* __restrict__ Ebp) {
  __shared__ float S[128][68];   // +4 pad
  const int id = blockIdx.x, tid = threadIdx.x;
  const int mt = id >> 4, t = id & 15;
  const int m0 = mt * 128, n0 = t * 64;
#pragma unroll
  for (int i = 0; i < 8; i++) {
    int f = i * 256 + tid;         // 2048 float4s = 128 rows x 16
    int r = f >> 4, c4 = f & 15;
    float4 v = *(const float4*)(Bm + (size_t)(m0 + r) * 1024 + n0 + c4 * 4);
    *(float4*)&S[r][c4 * 4] = v;
  }
  __syncthreads();
#pragma unroll
  for (int i = 0; i < 2; i++) {
    int s = i * 256 + tid;         // 512 lane-slots (8 qcw x 64 lanes)
    int qcw = s >> 6, lane = s & 63;
    int col = lane & 15, quad = lane >> 4;
    int row = qcw * 16 + col;
    f16x8 h0, h1;
#pragma unroll
    for (int j = 0; j < 8; j++) {
      int jt = j >> 2, r = j & 3;
      h0[j] = (f16)__expf(S[row][jt * 16 + quad * 4 + r]);
    }
#pragma unroll
    for (int j = 0; j < 8; j++) {
      int jt = 2 + (j >> 2), r = j & 3;
      h1[j] = (f16)__expf(S[row][jt * 16 + quad * 4 + r]);
    }
    // lane-contiguous: h slabs of 512 f16 (64 lanes x 8)
    f16* out = Ebp + ((size_t)(id * 8 + qcw) * 2) * 512 + lane * 8;
    *(f16x8*)out = h0;
    *(f16x8*)(out + 512) = h1;
  }
}

// ---------------------------------------------------------------------------
// QKV GEMM v4: pure-DMA staging. grid (128 xt, 8 h, 3 z). BM=128 x BN=128 x
// BK=64, double-buffered, one barrier/iter. 512 thr = 8 waves.
// ---------------------------------------------------------------------------
__global__ __launch_bounds__(512) __attribute__((amdgpu_waves_per_eu(4, 4)))
void gemm_qkv(const f16* __restrict__ x1p, const f16* __restrict__ x2p,
              const f16* __restrict__ wp,
              const float* __restrict__ wqb, const float* __restrict__ wkb,
              const float* __restrict__ wvb,
              f16* __restrict__ Qp, f16* __restrict__ Kp, f16* __restrict__ Vp,
              float qscale) {
  __shared__ f16 Wl[2][8192];
  __shared__ f16 Xl[2][8192];
  const int z = blockIdx.z;
  const f16* Xp = (z == 0) ? x1p : x2p;
  const float* bias = (z == 0) ? wqb : (z == 1) ? wkb : wvb;
  f16* outp = (z == 0) ? Qp : (z == 1) ? Kp : Vp;
  const float sc = (z == 0) ? qscale : 1.0f;

  const int tid = threadIdx.x, lane = tid & 63, wid = tid >> 6;
  const int col = lane & 15, quad = lane >> 4;
  const int xt = blockIdx.x, h = blockIdx.y;
  const int wr = wid >> 2, xc = wid & 3;  // wave M-group / N-group
  const f16* Xb = Xp + (size_t)xt * 32768;
  const f16* Wb = wp + (size_t)z * 262144 + (size_t)h * 32768;

#define QISSUE(T, bufi)                                                   \
  {                                                                       \
    _Pragma("unroll") for (int j = 0; j < 2; j++) {                       \
      int lc = wid * 2 + j;                                               \
      int rt = lc >> 1, ksl = lc & 1;                                     \
      gl_lds16(Wb + (size_t)((rt * 8 + (T) * 2 + ksl) << 9) + lane * 8,   \
               &Wl[bufi][lc * 512]);                                      \
      gl_lds16(Xb + (size_t)((rt * 8 + (T) * 2 + ksl) << 9) + lane * 8,   \
               &Xl[bufi][lc * 512]);                                      \
    }                                                                     \
  }

  QISSUE(0, 0);
  QISSUE(1, 1);

  f32x4 acc[4][2];
#pragma unroll
  for (int i = 0; i < 4; i++)
#pragma unroll
    for (int j = 0; j < 2; j++) acc[i][j] = (f32x4){0.f, 0.f, 0.f, 0.f};

  __syncthreads();

  for (int t = 0; t < 4; ++t) {
    const int buf = t & 1;
    const f16* Ra = (z == 2) ? Xl[buf] : Wl[buf];  // A-operand (C rows)
    const f16* Cb = (z == 2) ? Wl[buf] : Xl[buf];  // B-operand (C cols)
#pragma unroll
    for (int ksl = 0; ksl < 2; ksl++) {
      f16x8 af[4], bf[2];
#pragma unroll
      for (int i = 0; i < 4; i++)
        af[i] = *(const f16x8*)&Ra[((wr * 4 + i) * 2 + ksl) * 512 + lane * 8];
#pragma unroll
      for (int j = 0; j < 2; j++)
        bf[j] = *(const f16x8*)&Cb[((xc * 2 + j) * 2 + ksl) * 512 + lane * 8];
#pragma unroll
      for (int i = 0; i < 4; i++)
#pragma unroll
        for (int j = 0; j < 2; j++) acc[i][j] = MFMA_F16(af[i], bf[j], acc[i][j]);
    }
    __syncthreads();
    if (t + 2 < 4) QISSUE(t + 2, buf);
  }

  if (z < 2) {
#pragma unroll
    for (int i = 0; i < 4; i++) {
      const int k0h = wr * 64 + i * 16 + quad * 4;
      float4 bq = *(const float4*)(bias + h * 128 + k0h);
      const int ks2 = k0h >> 5, q2 = (k0h >> 3) & 3, lo = k0h & 7;
#pragma unroll
      for (int j = 0; j < 2; j++) {
        const int bn2 = xt * 128 + xc * 32 + j * 16 + col;
        const int b = bn2 >> 10, n2 = bn2 & 1023;
        const int T = n2 >> 6, jt = (n2 >> 4) & 3, c2 = n2 & 15;
        f16x4 pk;
#pragma unroll
        for (int r = 0; r < 4; r++)
          pk[r] = (f16)((acc[i][j][r] + ((const float*)&bq)[r]) * sc);
        *(f16x4*)(outp + (size_t)(b * 8 + h) * 131072 + T * 8192 +
                  (jt * 4 + ks2) * 512 + (q2 * 16 + c2) * 8 + lo) = pk;
      }
    }
  } else {
#pragma unroll
    for (int j = 0; j < 2; j++) {
      const int d = xc * 32 + j * 16 + col;
      const float bv = bias[h * 128 + d];
      const int ct = d >> 4, cc = d & 15;
#pragma unroll
      for (int i = 0; i < 4; i++) {
        const int bn2 = xt * 128 + wr * 64 + i * 16 + quad * 4;
        const int b = bn2 >> 10, n2 = bn2 & 1023;
        const int T = n2 >> 6, kv6 = n2 & 63;
        const int ks2 = kv6 >> 5, qv = (kv6 >> 3) & 3, jj = kv6 & 7;
        f16x4 pk;
#pragma unroll
        for (int r = 0; r < 4; r++) pk[r] = (f16)(acc[i][j][r] + bv);
        *(f16x4*)(outp + (size_t)(b * 8 + h) * 131072 + T * 8192 +
                  (ct * 2 + ks2) * 512 + (qv * 16 + cc) * 8 + jj) = pk;
      }
    }
  }
}

// ---------------------------------------------------------------------------
// Proj GEMM: out[16384,128] = A[16384,1024](f16) @ W[128,1024]^T + b, fp32.
// ---------------------------------------------------------------------------
__global__ __launch_bounds__(256) void gemm_proj(const f16* __restrict__ A,
                                                 const float* __restrict__ W,
                                                 const float* __restrict__ bias,
                                                 float* __restrict__ out) {
  constexpr int LD = 72;
  __shared__ f16 As[64][LD];
  __shared__ f16 Bs[64][LD];
  const int tid = threadIdx.x, lane = tid & 63, wid = tid >> 6;
  const int col = lane & 15, quad = lane >> 4;
  const int wm = (wid >> 1) * 32, wn = (wid & 1) * 32;
  const int m0 = blockIdx.x * 64, n0 = blockIdx.y * 64;

  f32x4 acc[2][2];
#pragma unroll
  for (int i = 0; i < 2; i++)
#pragma unroll
    for (int j = 0; j < 2; j++) acc[i][j] = (f32x4){0.f, 0.f, 0.f, 0.f};

  for (int kt = 0; kt < 16; ++kt) {
    const int k0 = kt * 64;
#pragma unroll
    for (int i = 0; i < 2; i++) {
      int f = i * 256 + tid;
      int r = f >> 3, ch = f & 7;
      *(f16x8*)&As[r][ch * 8] = *(const f16x8*)(A + (size_t)(m0 + r) * 1024 + k0 + ch * 8);
    }
#pragma unroll
    for (int i = 0; i < 4; i++) {
      int f = i * 256 + tid;
      int r = f >> 4, c4 = f & 15;
      float4 v = *(const float4*)(W + (size_t)(n0 + r) * 1024 + k0 + c4 * 4);
      f16x4 hh; hh[0] = (f16)v.x; hh[1] = (f16)v.y; hh[2] = (f16)v.z; hh[3] = (f16)v.w;
      *(f16x4*)&Bs[r][c4 * 4] = hh;
    }
    __syncthreads();
#pragma unroll
    for (int ks = 0; ks < 2; ks++) {
      f16x8 af[2], bf[2];
#pragma unroll
      for (int i = 0; i < 2; i++) af[i] = *(const f16x8*)&As[wm + i * 16 + col][ks * 32 + quad * 8];
#pragma unroll
      for (int j = 0; j < 2; j++) bf[j] = *(const f16x8*)&Bs[wn + j * 16 + col][ks * 32 + quad * 8];
#pragma unroll
      for (int i = 0; i < 2; i++)
#pragma unroll
        for (int j = 0; j < 2; j++) acc[i][j] = MFMA_F16(af[i], bf[j], acc[i][j]);
    }
    __syncthreads();
  }
#pragma unroll
  for (int j = 0; j < 2; j++) {
    const int c = n0 + wn + j * 16 + col;
    const float bv = bias[c];
#pragma unroll
    for (int i = 0; i < 2; i++) {
      const int r0 = m0 + wm + i * 16 + quad * 4;
#pragma unroll
      for (int r = 0; r < 4; r++)
        out[(size_t)(r0 + r) * 128 + c] = acc[i][j][r] + bv;
    }
  }
}

// ---------------------------------------------------------------------------
// Fused attention v10 (R10): 512 thr = 8 waves x 32 q-rows = 256 q-rows/block,
// kv-tile 64, gl_lds double-buffer, one barrier/iter, Eb f16 exp-bias.
// Grid 512 (b=id>>5, h=id&7, mt=(id>>3)&3). K/V re-read amplification 8 -> 4.
// LDS = K 32K + V 32K + Ps 32K = 96KB -> 1 block/CU (8 waves = 2/SIMD, same
// wave count as R9's 2x4). Per-wave register state identical to R9.
// ---------------------------------------------------------------------------
__global__ __launch_bounds__(512, 2)
void attn_fused(const f16* __restrict__ Qp, const f16* __restrict__ Kp,
                const f16* __restrict__ Vp, const f16* __restrict__ Ebp,
                f16* __restrict__ O) {
  __shared__ f16 Ksl[2][8192];
  __shared__ f16 Vtl[2][8192];
  __shared__ f16 Ps[16384];
  const int tid = threadIdx.x, lane = tid & 63, wid = tid >> 6;  // wid 0..7
  const int col = lane & 15, quad = lane >> 4;
  const int id = blockIdx.x;
  const int mt = (id >> 3) & 3;                       // 4 m-tiles of 256 rows
  const int bh = ((id >> 5) << 3) | (id & 7);         // b = id>>5, h = id&7
  const int b = bh >> 3, h = bh & 7;
  const int m0 = mt * 256;
  const int wm = wid * 32;  // wave's 32 q-rows within the 256-row tile

  const f16* Qb = Qp + (size_t)bh * 131072;
  const f16* Kb = Kp + (size_t)bh * 131072;
  const f16* Vb = Vp + (size_t)bh * 131072;
  // Eb base: 128-row tile index = mt*2 + (wid>>2); qcw = (wid&3)*2 + qc.
  // slab(tile128*16+t, qcw, h) = ((tile*8+qcw)*2+h)*512 + lane*8
  const int tile128 = mt * 2 + (wid >> 2);
  const f16* Ebw = Ebp +
      (((size_t)tile128 * 16 * 8 + (wid & 3) * 2) * 2) * 512 + lane * 8;

  // waves 0-3 stage K chunks (4 each), waves 4-7 stage V chunks (4 each)
#define AISSUE(T, bufi)                                                       \
  {                                                                           \
    if (wid < 4) {                                                            \
      _Pragma("unroll") for (int j = 0; j < 4; j++)                           \
          gl_lds16(Kb + (size_t)(T) * 8192 + (wid * 4 + j) * 512 + lane * 8,  \
                   &Ksl[bufi][(wid * 4 + j) * 512]);                          \
    } else {                                                                  \
      _Pragma("unroll") for (int j = 0; j < 4; j++)                           \
          gl_lds16(Vb + (size_t)(T) * 8192 + ((wid - 4) * 4 + j) * 512 + lane * 8, \
                   &Vtl[bufi][((wid - 4) * 4 + j) * 512]);                    \
    }                                                                         \
  }

  AISSUE(0, 0);
  AISSUE(1, 1);

  f16x8 qf[2][4];
#pragma unroll
  for (int qc = 0; qc < 2; qc++) {
    const int m = m0 + wm + qc * 16;
    const int T = m >> 6, jt2 = (m >> 4) & 3;
#pragma unroll
    for (int ks = 0; ks < 4; ks++)
      qf[qc][ks] = *(const f16x8*)(Qb + T * 8192 + (jt2 * 4 + ks) * 512 + lane * 8);
  }

  f32x4 oacc[2][8];
  float l[2] = {0.f, 0.f};
#pragma unroll
  for (int qc = 0; qc < 2; qc++)
#pragma unroll
    for (int ct = 0; ct < 8; ct++) oacc[qc][ct] = (f32x4){0.f, 0.f, 0.f, 0.f};

  __syncthreads();

  for (int t = 0; t < 16; ++t) {
    const int buf = t & 1;

    // exp-bias: 4 lane-contiguous f16x8 loads (16B lane stride)
    f16x8 ebA[2], ebB[2];
    {
      const f16* Et = Ebw + (size_t)t * 8192;
      ebA[0] = *(const f16x8*)(Et);
      ebB[0] = *(const f16x8*)(Et + 512);
      ebA[1] = *(const f16x8*)(Et + 1024);
      ebB[1] = *(const f16x8*)(Et + 1536);
    }

    f32x4 s[2][4];
#pragma unroll
    for (int qc = 0; qc < 2; qc++)
#pragma unroll
      for (int jt = 0; jt < 4; jt++) s[qc][jt] = (f32x4){0.f, 0.f, 0.f, 0.f};
#pragma unroll
    for (int ks = 0; ks < 4; ks++) {
      f16x8 kf[4];
#pragma unroll
      for (int jt = 0; jt < 4; jt++)
        kf[jt] = *(const f16x8*)&Ksl[buf][(jt * 4 + ks) * 512 + lane * 8];
#pragma unroll
      for (int jt = 0; jt < 4; jt++)
#pragma unroll
        for (int qc = 0; qc < 2; qc++)
          s[qc][jt] = MFMA_F16(kf[jt], qf[qc][ks], s[qc][jt]);
    }

#pragma unroll
    for (int qc = 0; qc < 2; qc++) {
      const int m = wm + qc * 16 + col;
#pragma unroll
      for (int jt = 0; jt < 4; jt++) {
        float p0, p1, p2, p3;
        if (jt < 2) {
          p0 = __expf(s[qc][jt][0]) * (float)ebA[qc][(jt & 1) * 4 + 0];
          p1 = __expf(s[qc][jt][1]) * (float)ebA[qc][(jt & 1) * 4 + 1];
          p2 = __expf(s[qc][jt][2]) * (float)ebA[qc][(jt & 1) * 4 + 2];
          p3 = __expf(s[qc][jt][3]) * (float)ebA[qc][(jt & 1) * 4 + 3];
        } else {
          p0 = __expf(s[qc][jt][0]) * (float)ebB[qc][(jt & 1) * 4 + 0];
          p1 = __expf(s[qc][jt][1]) * (float)ebB[qc][(jt & 1) * 4 + 1];
          p2 = __expf(s[qc][jt][2]) * (float)ebB[qc][(jt & 1) * 4 + 2];
          p3 = __expf(s[qc][jt][3]) * (float)ebB[qc][(jt & 1) * 4 + 3];
        }
        l[qc] += (p0 + p1) + (p2 + p3);
        f16x4 pk; pk[0] = (f16)p0; pk[1] = (f16)p1; pk[2] = (f16)p2; pk[3] = (f16)p3;
        const int g = (jt * 2 + (quad >> 1)) ^ (col & 7);
        *(f16x4*)&Ps[m * 64 + g * 8 + (quad & 1) * 4] = pk;
      }
    }

#pragma unroll
    for (int ks = 0; ks < 2; ks++) {
      f16x8 pf[2];
#pragma unroll
      for (int qc = 0; qc < 2; qc++) {
        const int m = wm + qc * 16 + col;
        const int g = (ks * 4 + quad) ^ (col & 7);
        pf[qc] = *(const f16x8*)&Ps[m * 64 + g * 8];
      }
#pragma unroll
      for (int ct = 0; ct < 8; ct++) {
        f16x8 vf = *(const f16x8*)&Vtl[buf][(ct * 2 + ks) * 512 + lane * 8];
#pragma unroll
        for (int qc = 0; qc < 2; qc++)
          oacc[qc][ct] = MFMA_F16(pf[qc], vf, oacc[qc][ct]);
      }
    }

    __syncthreads();
    if (t + 2 < 16) AISSUE(t + 2, buf);
  }

#pragma unroll
  for (int qc = 0; qc < 2; qc++) {
    float lw = l[qc];
    lw += __shfl_xor(lw, 16);
    lw += __shfl_xor(lw, 32);
    f16* Ob = O + ((size_t)(b * 1024 + m0 + wm + qc * 16)) * 1024 + h * 128;
#pragma unroll
    for (int r = 0; r < 4; r++) {
      const float lv = __shfl(lw, (lane & 48) | (quad * 4 + r));
      const float inv = 1.0f / lv;
#pragma unroll
      for (int ct = 0; ct < 8; ct++)
        Ob[(size_t)(quad * 4 + r) * 1024 + ct * 16 + col] = (f16)(oacc[qc][ct][r] * inv);
    }
  }
}

extern "C" void kernel_launch(void* const* d_in, const int* in_sizes, int n_in,
                              void* d_out, int out_size, void* d_ws, size_t ws_size,
                              hipStream_t stream) {
  (void)in_sizes; (void)n_in; (void)out_size; (void)ws_size;
  const float* x1  = (const float*)d_in[0];
  const float* x2  = (const float*)d_in[1];
  const float* Bm  = (const float*)d_in[2];
  const float* wq  = (const float*)d_in[3];
  const float* wqb = (const float*)d_in[4];
  const float* wk  = (const float*)d_in[5];
  const float* wkb = (const float*)d_in[6];
  const float* wv  = (const float*)d_in[7];
  const float* wvb = (const float*)d_in[8];
  const float* pw  = (const float*)d_in[9];
  const float* pb  = (const float*)d_in[10];
  float* out = (float*)d_out;

  const size_t MiB = 1024 * 1024;
  f16* Qp  = (f16*)d_ws;                            // 0..32 MiB
  f16* Kp  = (f16*)((char*)d_ws + 32 * MiB);        // 32..64
  f16* Vp  = (f16*)((char*)d_ws + 64 * MiB);        // 64..96
  f16* Ow  = (f16*)((char*)d_ws + 96 * MiB);        // 96..128 (attn output)
  // packed inputs: alive only conv->qkv, then overlaid by Ow
  f16* x1p = (f16*)((char*)d_ws + 96 * MiB);        // 8 MiB
  f16* x2p = (f16*)((char*)d_ws + 104 * MiB);       // 8 MiB
  f16* wp  = (f16*)((char*)d_ws + 112 * MiB);       // 1.5 MiB
  // Packed exp-bias in d_out's first 2 MiB (out is 8 MiB fp32): written by
  // pack_eb pre-attn, read by attn, overwritten by gemm_proj at the end.
  f16* Ebp = (f16*)d_out;

  const float scale = 0.0883883476483184f;  // 1/sqrt(128)
  conv_pack<<<dim3(280), dim3(256), 0, stream>>>(x1, x2, wq, wk, wv, x1p, x2p, wp);
  pack_eb<<<dim3(128), dim3(256), 0, stream>>>(Bm, Ebp);
  gemm_qkv<<<dim3(128, 8, 3), dim3(512), 0, stream>>>(x1p, x2p, wp, wqb, wkb, wvb,
                                                      Qp, Kp, Vp, scale);
  attn_fused<<<dim3(512), dim3(512), 0, stream>>>(Qp, Kp, Vp, Ebp, Ow);
  gemm_proj<<<dim3(256, 2), dim3(256), 0, stream>>>(Ow, pw, pb, out);
}